// Round 9
// baseline (7124.555 us; speedup 1.0000x reference)
//
#include <hip/hip_runtime.h>
#include <hip/hip_cooperative_groups.h>

namespace cg = cooperative_groups;

typedef __attribute__((ext_vector_type(4))) float f32x4;
typedef __attribute__((ext_vector_type(8))) short bf16x8;
typedef unsigned short u16;
typedef unsigned int u32;
typedef __attribute__((ext_vector_type(4))) unsigned short u16x4;

#define EPS 1.1920929e-07f
#define S 1024
#define D 1024
#define NV 151936
#define NCYC 28
#define SMEM_BYTES 49152

__device__ __forceinline__ u16 f2bf(float f) {  // RNE
  u32 u = __float_as_uint(f);
  return (u16)((u + 0x7fffu + ((u >> 16) & 1u)) >> 16);
}
__device__ __forceinline__ float bf2f(u16 h) {
  return __uint_as_float((u32)h << 16);
}
struct bfpair { u16 h, l; };
__device__ __forceinline__ bfpair split_bf(float v) {
  bfpair r;
  r.h = f2bf(v);
  r.l = f2bf(v - bf2f(r.h));
  return r;
}

__device__ __forceinline__ void gl16(const void* g, void* s) {
  __builtin_amdgcn_global_load_lds((const __attribute__((address_space(1))) u32*)g,
                                   (__attribute__((address_space(3))) u32*)s, 16, 0, 0);
}

// safe for repeated calls (sync protects sbuf reuse)
__device__ __forceinline__ float block_sum256(float v, float* sbuf) {
  #pragma unroll
  for (int off = 32; off; off >>= 1) v += __shfl_down(v, off);
  int lane = threadIdx.x & 63, w = threadIdx.x >> 6;
  __syncthreads();
  if (lane == 0) sbuf[w] = v;
  __syncthreads();
  return sbuf[0] + sbuf[1] + sbuf[2] + sbuf[3];
}

// ---------------- f32 -> bf16 (RNE) ----------------
__global__ void k_cvt(const float* __restrict__ src, u16* __restrict__ dst, size_t n4) {
  size_t i = (size_t)blockIdx.x * 256 + threadIdx.x;
  size_t stride = (size_t)gridDim.x * 256;
  for (; i < n4; i += stride) {
    f32x4 v = ((const f32x4*)src)[i];
    u16x4 o;
    #pragma unroll
    for (int e = 0; e < 4; ++e) o[e] = f2bf(v[e]);
    ((u16x4*)dst)[i] = o;
  }
}

// ---------------- f32 -> (hi, lo) bf16 split ----------------
__global__ void k_cvt2(const float* __restrict__ src, u16* __restrict__ dh,
                       u16* __restrict__ dl, size_t n4) {
  size_t i = (size_t)blockIdx.x * 256 + threadIdx.x;
  size_t stride = (size_t)gridDim.x * 256;
  for (; i < n4; i += stride) {
    f32x4 v = ((const f32x4*)src)[i];
    u16x4 oh, ol;
    #pragma unroll
    for (int e = 0; e < 4; ++e) { bfpair p = split_bf(v[e]); oh[e] = p.h; ol[e] = p.l; }
    ((u16x4*)dh)[i] = oh;
    ((u16x4*)dl)[i] = ol;
  }
}

// ================= shared device phases (used by coop kernel AND fallback) =========

// gather + initial colpart; blocks 0..255
__device__ void gather_phase(const int* tokens, const float* embed,
                             float* x, u16* xh, u16* xl, float* cp) {
  const int t = threadIdx.x;
  if (blockIdx.x >= 256) return;
  f32x4 creg = 0.f;
  for (int rr = 0; rr < 4; ++rr) {
    int s = blockIdx.x * 4 + rr;
    int tok = tokens[s];
    f32x4 v = ((const f32x4*)(embed + (size_t)tok * D))[t];
    u16x4 oh, ol;
    #pragma unroll
    for (int e = 0; e < 4; ++e) { bfpair p = split_bf(v[e]); oh[e] = p.h; ol[e] = p.l; }
    ((f32x4*)(x + (size_t)s * D))[t] = v;
    ((u16x4*)(xh + (size_t)s * D))[t] = oh;
    ((u16x4*)(xl + (size_t)s * D))[t] = ol;
    creg += v;
  }
  *(f32x4*)(cp + (size_t)blockIdx.x * D + t * 4) = creg;
}

// 64x64-tile split-bf16 GEMM over 1024xD output, 256 tiles, single-buffered (32 KB)
template <bool CADD>
__device__ void gemm64_phase(char* smem, const u16* Ah_, const u16* Al_,
                             const u16* Bh_, const u16* Bl_, int K,
                             float* xout, u16* xho, u16* xlo, float* Cout, int G) {
  const int t = threadIdx.x;
  u16* Ash = (u16*)smem;          // 4096 u16 each
  u16* Asl = Ash + 4096;
  u16* Bsh = Asl + 4096;
  u16* Bsl = Bsh + 4096;
  const int wave = t >> 6, lane = t & 63;
  const int fr = lane & 15, kb = lane >> 4;
  const int sr = t >> 3, skc = (t & 7) << 3;
  const int sswz = skc ^ ((sr & 7) << 3);
  for (int tile = blockIdx.x; tile < 256; tile += G) {
    const int m0 = (tile >> 4) * 64, n0 = (tile & 15) * 64;
    f32x4 acc[4];
    #pragma unroll
    for (int j = 0; j < 4; ++j) acc[j] = 0.f;

    for (int k0 = 0; k0 < K; k0 += 64) {
      #pragma unroll
      for (int it = 0; it < 2; ++it) {
        int r = it * 32 + sr;
        size_t ga = (size_t)(m0 + r) * K + k0 + sswz;
        size_t gb = (size_t)(n0 + r) * K + k0 + sswz;
        int so = r * 64 + skc;
        gl16(Ah_ + ga, Ash + so);
        gl16(Al_ + ga, Asl + so);
        gl16(Bh_ + gb, Bsh + so);
        gl16(Bl_ + gb, Bsl + so);
      }
      __syncthreads();
      #pragma unroll
      for (int ks = 0; ks < 2; ++ks) {
        const int cphys = (ks * 32 + kb * 8) ^ ((fr & 7) << 3);
        int oa = (wave * 16 + fr) * 64 + cphys;
        bf16x8 ah = *(const bf16x8*)&Ash[oa];
        bf16x8 al = *(const bf16x8*)&Asl[oa];
        #pragma unroll
        for (int j = 0; j < 4; ++j) {
          int ob = (j * 16 + fr) * 64 + cphys;
          bf16x8 bh = *(const bf16x8*)&Bsh[ob];
          bf16x8 bl = *(const bf16x8*)&Bsl[ob];
          acc[j] = __builtin_amdgcn_mfma_f32_16x16x32_bf16(ah, bh, acc[j], 0, 0, 0);
          acc[j] = __builtin_amdgcn_mfma_f32_16x16x32_bf16(ah, bl, acc[j], 0, 0, 0);
          acc[j] = __builtin_amdgcn_mfma_f32_16x16x32_bf16(al, bh, acc[j], 0, 0, 0);
        }
      }
      __syncthreads();
    }
    #pragma unroll
    for (int j = 0; j < 4; ++j)
      #pragma unroll
      for (int rg = 0; rg < 4; ++rg) {
        int m = m0 + wave * 16 + kb * 4 + rg;
        int n = n0 + j * 16 + fr;
        if (CADD) {
          float v = xout[(size_t)m * D + n] + acc[j][rg];
          xout[(size_t)m * D + n] = v;
          bfpair p = split_bf(v);
          xho[(size_t)m * D + n] = p.h;
          xlo[(size_t)m * D + n] = p.l;
        } else {
          Cout[(size_t)m * D + n] = acc[j][rg];
        }
      }
  }
}

// causal EMA windowed conv -> split; 256 tiles of 64x64 (40.7 KB smem)
__device__ void causal_phase(char* smem, const float* x, u16* Rh, u16* Rl,
                             float dec, int G) {
  const int t = threadIdx.x;
  for (int tile = blockIdx.x; tile < 256; tile += G) {
    int s0 = (tile >> 4) * 64, d0 = (tile & 15) * 64;
    float (*tl)[64] = (float(*)[64])smem;  // [159][64]
    for (int idx = t; idx < 159 * 64; idx += 256) {
      int rr = idx >> 6, c = idx & 63;
      int gs = s0 - 95 + rr;
      tl[rr][c] = (gs >= 0) ? x[(size_t)gs * D + d0 + c] : 0.f;
    }
    __syncthreads();
    int c = t & 63, r0 = t >> 6;
    for (int rr = r0; rr < 64; rr += 4) {
      float acc = 0.f, w = 1.f - dec;
      int base = rr + 95;
      #pragma unroll 8
      for (int j = 0; j < 96; ++j) { acc += w * tl[base - j][c]; w *= dec; }
      bfpair p = split_bf(acc);
      Rh[(size_t)(s0 + rr) * D + d0 + c] = p.h;
      Rl[(size_t)(s0 + rr) * D + d0 + c] = p.l;
    }
    __syncthreads();
  }
}

// proj GEMM, k-split x4: blocks 0..63 = (mt = b&15, kq = b>>4); 48 KB smem
__device__ void proj_phase(char* smem, const u16* xh, const u16* xl,
                           const u16* Bh_, const u16* Bl_, float* pacc) {
  const int t = threadIdx.x;
  const int mt = blockIdx.x & 15, kq = blockIdx.x >> 4;
  const int m0 = mt * 64;
  const int kbase = kq * 256;
  u16* Ash = (u16*)smem;       // 4096 u16
  u16* Asl = Ash + 4096;
  u16* Bsh = Asl + 4096;       // 8192 u16
  u16* Bsl = Bsh + 8192;
  const int wave = t >> 6, lane = t & 63;
  const int fr = lane & 15, kb = lane >> 4;
  const int sr = t >> 3, skc = (t & 7) << 3;
  const int sswz = skc ^ ((sr & 7) << 3);
  f32x4 acc[8];
  #pragma unroll
  for (int j = 0; j < 8; ++j) acc[j] = 0.f;

  for (int kt = 0; kt < 4; ++kt) {
    int k0 = kbase + kt * 64;
    #pragma unroll
    for (int it = 0; it < 2; ++it) {
      int r = it * 32 + sr;
      size_t ga = (size_t)(m0 + r) * D + k0 + sswz;
      gl16(xh + ga, Ash + r * 64 + skc);
      gl16(xl + ga, Asl + r * 64 + skc);
    }
    #pragma unroll
    for (int it = 0; it < 4; ++it) {
      int r = it * 32 + sr;
      size_t gb = (size_t)r * D + k0 + sswz;
      gl16(Bh_ + gb, Bsh + r * 64 + skc);
      gl16(Bl_ + gb, Bsl + r * 64 + skc);
    }
    __syncthreads();
    #pragma unroll
    for (int ks = 0; ks < 2; ++ks) {
      const int cphys = (ks * 32 + kb * 8) ^ ((fr & 7) << 3);
      int oa = (wave * 16 + fr) * 64 + cphys;
      bf16x8 ah = *(const bf16x8*)&Ash[oa];
      bf16x8 al = *(const bf16x8*)&Asl[oa];
      #pragma unroll
      for (int j = 0; j < 8; ++j) {
        int ob = (j * 16 + fr) * 64 + cphys;
        bf16x8 bh = *(const bf16x8*)&Bsh[ob];
        bf16x8 bl = *(const bf16x8*)&Bsl[ob];
        acc[j] = __builtin_amdgcn_mfma_f32_16x16x32_bf16(ah, bh, acc[j], 0, 0, 0);
        acc[j] = __builtin_amdgcn_mfma_f32_16x16x32_bf16(ah, bl, acc[j], 0, 0, 0);
        acc[j] = __builtin_amdgcn_mfma_f32_16x16x32_bf16(al, bh, acc[j], 0, 0, 0);
      }
    }
    __syncthreads();
  }
  float* pb = pacc + (size_t)blockIdx.x * 64 * 128;
  #pragma unroll
  for (int j = 0; j < 8; ++j)
    #pragma unroll
    for (int rg = 0; rg < 4; ++rg) {
      int ml = wave * 16 + kb * 4 + rg;
      pb[ml * 128 + j * 16 + fr] = acc[j][rg];
    }
}

// angles for plane p; fused colsum over cp[256]
__device__ void angles_phase(int p, const float* cp, const float* agw,
                             const float* bang_i, float* trig, float* sbuf) {
  const int t = threadIdx.x;
  float sum = 0.f;
  #pragma unroll
  for (int q = 0; q < 4; ++q) {
    int d = t + q * 256;
    float cs = 0.f;
    #pragma unroll 8
    for (int b = 0; b < 256; ++b) cs += cp[b * D + d];
    sum += cs * agw[p * D + d];
  }
  float total = block_sum256(sum, sbuf);
  if (t == 0) {
    float ang = bang_i[p] + 0.1f * (total * (1.f / (float)S));
    trig[p] = cosf(ang);
    trig[64 + p] = sinf(ang);
  }
}

// rot: blocks 0..15 reduce 4 k-partials + rotate -> split roth/rotl
__device__ void rot_phase(const float* pacc, const float* trig,
                          u16* roth, u16* rotl) {
  const int t = threadIdx.x;
  const int mt = blockIdx.x;
  if (mt >= 16) return;
  const int r = t >> 2, quad = t & 3;
  const int row = mt * 64 + r;
  #pragma unroll
  for (int cc = 0; cc < 4; ++cc) {
    int p = quad * 16 + cc * 4;
    f32x4 av = 0.f, bv = 0.f;
    #pragma unroll
    for (int kq = 0; kq < 4; ++kq) {
      const float* pk = pacc + ((size_t)(kq * 16 + mt) * 64 + r) * 128;
      av += *(const f32x4*)(pk + p);
      bv += *(const f32x4*)(pk + 64 + p);
    }
    f32x4 ca = *(const f32x4*)(trig + p);
    f32x4 sa = *(const f32x4*)(trig + 64 + p);
    u16x4 h0, l0, h1, l1;
    #pragma unroll
    for (int e = 0; e < 4; ++e) {
      float ra = av[e] * ca[e] - bv[e] * sa[e];
      float rb = av[e] * sa[e] + bv[e] * ca[e];
      bfpair pa = split_bf(ra);
      bfpair pb = split_bf(rb);
      h0[e] = pa.h; l0[e] = pa.l;
      h1[e] = pb.h; l1[e] = pb.l;
    }
    *(u16x4*)(roth + row * 128 + p) = h0;
    *(u16x4*)(rotl + row * 128 + p) = l0;
    *(u16x4*)(roth + row * 128 + 64 + p) = h1;
    *(u16x4*)(rotl + row * 128 + 64 + p) = l1;
  }
}

// epilogue (+ fused colpart): blocks 0..255, 4 rows each
__device__ void epilogue_phase(float* sbuf, float* x, u16* xh, u16* xl,
                               const float* Rf, const float* scale,
                               const float* shift, const float* nw, float* cp) {
  const int t = threadIdx.x;
  if (blockIdx.x >= 256) return;
  f32x4 sc = *(const f32x4*)(scale + t * 4);
  f32x4 sh = *(const f32x4*)(shift + t * 4);
  f32x4 nwv = *(const f32x4*)(nw + t * 4);
  f32x4 creg = 0.f;
  for (int rr = 0; rr < 4; ++rr) {
    int s = blockIdx.x * 4 + rr;
    f32x4 xv = *(const f32x4*)(x + (size_t)s * D + t * 4);
    f32x4 rv = *(const f32x4*)(Rf + (size_t)s * D + t * 4);
    float y[4], ss = 0.f;
    #pragma unroll
    for (int c = 0; c < 4; ++c) {
      float xr = xv[c] + rv[c];
      float tt = xr * sc[c] + sh[c];
      float act = tt / (1.f + expf(-tt));
      y[c] = act - xv[c];
      ss += y[c] * y[c];
    }
    float total = block_sum256(ss, sbuf);
    float inv = rsqrtf(total * (1.f / (float)D) + EPS);
    f32x4 o;
    u16x4 oh, ol;
    #pragma unroll
    for (int c = 0; c < 4; ++c) {
      o[c] = xv[c] + y[c] * inv * nwv[c];
      bfpair p = split_bf(o[c]);
      oh[c] = p.h;
      ol[c] = p.l;
      creg[c] += o[c];
    }
    *(f32x4*)(x + (size_t)s * D + t * 4) = o;
    *(u16x4*)(xh + (size_t)s * D + t * 4) = oh;
    *(u16x4*)(xl + (size_t)s * D + t * 4) = ol;
  }
  *(f32x4*)(cp + (size_t)blockIdx.x * D + t * 4) = creg;
}

// final rmsnorm -> bf16: blocks 0..255, 4 rows each
__device__ void outnorm_phase(float* sbuf, const float* x, const float* w, u16* xn) {
  const int t = threadIdx.x;
  if (blockIdx.x >= 256) return;
  for (int rr = 0; rr < 4; ++rr) {
    int s = blockIdx.x * 4 + rr;
    f32x4 xv = *(const f32x4*)(x + (size_t)s * D + t * 4);
    float total = block_sum256(xv[0]*xv[0] + xv[1]*xv[1] + xv[2]*xv[2] + xv[3]*xv[3], sbuf);
    float inv = rsqrtf(total * (1.f / (float)D) + EPS);
    f32x4 wv = *(const f32x4*)(w + t * 4);
    u16x4 o;
    #pragma unroll
    for (int c = 0; c < 4; ++c) o[c] = f2bf(xv[c] * inv * wv[c]);
    *(u16x4*)(xn + (size_t)s * D + t * 4) = o;
  }
}

// ================= cooperative persistent kernel =================
__global__ __launch_bounds__(256) void k_loop(
    const int* __restrict__ tokens, const float* __restrict__ embed,
    const float* __restrict__ bang, const float* __restrict__ agw,
    const float* __restrict__ scales, const float* __restrict__ shifts,
    const float* __restrict__ normw, const float* __restrict__ decay,
    const float* __restrict__ onorm,
    const u16* __restrict__ gate_h, const u16* __restrict__ gate_l,
    const u16* __restrict__ Wp_h, const u16* __restrict__ Wp_l,
    const u16* __restrict__ Wb_h, const u16* __restrict__ Wb_l,
    float* x, u16* xh, u16* xl, u16* Rh, u16* Rl, float* Rf,
    float* pacc, u16* roth, u16* rotl, float* cp, float* trig, u16* xn) {
  __shared__ __align__(16) char smem[SMEM_BYTES];
  __shared__ float sbuf[4];
  cg::grid_group g2 = cg::this_grid();
  const int G = gridDim.x;
  const float dec = 1.f / (1.f + expf(-decay[0]));

  gather_phase(tokens, embed, x, xh, xl, cp);
  g2.sync();

  for (int i = 0; i < NCYC; ++i) {
    const u16* Wph = Wp_h + (size_t)i * 128 * D;
    const u16* Wpl = Wp_l + (size_t)i * 128 * D;
    const u16* Wbh = Wb_h + (size_t)i * 128 * D;
    const u16* Wbl = Wb_l + (size_t)i * 128 * D;

    if ((i & 3) == 0) {
      causal_phase(smem, x, Rh, Rl, dec, G);
      g2.sync();
      gemm64_phase<true>(smem, Rh, Rl, gate_h, gate_l, 1024, x, xh, xl, nullptr, G);
      g2.sync();
    }
    if (blockIdx.x < 64) proj_phase(smem, xh, xl, Wph, Wpl, pacc);
    else if (blockIdx.x < 128) angles_phase(blockIdx.x - 64, cp, agw, bang + i * 64, trig, sbuf);
    g2.sync();
    rot_phase(pacc, trig, roth, rotl);
    g2.sync();
    gemm64_phase<false>(smem, roth, rotl, Wbh, Wbl, 128, nullptr, nullptr, nullptr, Rf, G);
    g2.sync();
    epilogue_phase(sbuf, x, xh, xl, Rf, scales + i * D, shifts + i * D, normw + i * D, cp);
    g2.sync();
  }
  outnorm_phase(sbuf, x, onorm, xn);
}

// ================= fallback wrappers (regular launches, same math) =================
__global__ __launch_bounds__(256) void fb_gather(const int* tokens, const float* embed,
                                                 float* x, u16* xh, u16* xl, float* cp) {
  gather_phase(tokens, embed, x, xh, xl, cp);
}
__global__ __launch_bounds__(256) void fb_causal(const float* x, u16* Rh, u16* Rl,
                                                 const float* decay) {
  __shared__ __align__(16) char sm[40704];
  causal_phase(sm, x, Rh, Rl, 1.f / (1.f + expf(-decay[0])), gridDim.x);
}
__global__ __launch_bounds__(256) void fb_gate(const u16* Rh, const u16* Rl,
                                               const u16* gh, const u16* gl,
                                               float* x, u16* xh, u16* xl) {
  __shared__ __align__(16) char sm[32768];
  gemm64_phase<true>(sm, Rh, Rl, gh, gl, 1024, x, xh, xl, nullptr, gridDim.x);
}
__global__ __launch_bounds__(256) void fb_projang(const u16* xh, const u16* xl,
                                                  const u16* Wph, const u16* Wpl,
                                                  const float* cp, const float* agw,
                                                  const float* bang_i,
                                                  float* pacc, float* trig) {
  __shared__ __align__(16) char sm[SMEM_BYTES];
  __shared__ float sbuf[4];
  if (blockIdx.x < 64) proj_phase(sm, xh, xl, Wph, Wpl, pacc);
  else angles_phase(blockIdx.x - 64, cp, agw, bang_i, trig, sbuf);
}
__global__ __launch_bounds__(256) void fb_rot(const float* pacc, const float* trig,
                                              u16* roth, u16* rotl) {
  rot_phase(pacc, trig, roth, rotl);
}
__global__ __launch_bounds__(256) void fb_back(const u16* roth, const u16* rotl,
                                               const u16* Wbh, const u16* Wbl, float* Rf) {
  __shared__ __align__(16) char sm[32768];
  gemm64_phase<false>(sm, roth, rotl, Wbh, Wbl, 128, nullptr, nullptr, nullptr, Rf, gridDim.x);
}
__global__ __launch_bounds__(256) void fb_epi(float* x, u16* xh, u16* xl, const float* Rf,
                                              const float* scale, const float* shift,
                                              const float* nw, float* cp) {
  __shared__ float sbuf[4];
  epilogue_phase(sbuf, x, xh, xl, Rf, scale, shift, nw, cp);
}
__global__ __launch_bounds__(256) void fb_outnorm(const float* x, const float* w, u16* xn) {
  __shared__ float sbuf[4];
  outnorm_phase(sbuf, x, w, xn);
}

// ---------------- lm_head GEMM: no-LDS direct-to-register, XCD-chunk swizzle -------
template <bool PRECONV>
__global__ __launch_bounds__(256) void k_lm(const u16* __restrict__ A,
                                            const void* __restrict__ Wsrc,
                                            float* __restrict__ out) {
  const int bid = blockIdx.x;
  const int lid = (bid & 7) * 1187 + (bid >> 3);  // bijective: 9496 = 8*1187
  const int m0 = (lid & 7) * 128;
  const int n0 = (lid >> 3) * 128;
  const int t = threadIdx.x;
  const int wave = t >> 6, lane = t & 63;
  const int wm = (wave >> 1) * 64, wn = (wave & 1) * 64;
  const int fr = lane & 15, kb = lane >> 4;
  const u16* Wb16 = (const u16*)Wsrc;
  const float* Wf = (const float*)Wsrc;

  const u16* ap[4];
  const u16* bp[4];
  const float* bpf[4];
  #pragma unroll
  for (int i = 0; i < 4; ++i)
    ap[i] = A + (size_t)(m0 + wm + i * 16 + fr) * D + kb * 8;
  #pragma unroll
  for (int j = 0; j < 4; ++j) {
    int n = n0 + wn + j * 16 + fr;
    if (PRECONV) bp[j] = Wb16 + (size_t)n * D + kb * 8;
    else bpf[j] = Wf + (size_t)n * D + kb * 8;
  }

  f32x4 acc[4][4];
  #pragma unroll
  for (int i = 0; i < 4; ++i)
    #pragma unroll
    for (int j = 0; j < 4; ++j) acc[i][j] = 0.f;

  #pragma unroll 4
  for (int kc = 0; kc < 32; ++kc) {
    bf16x8 a[4], b[4];
    #pragma unroll
    for (int i = 0; i < 4; ++i) a[i] = *(const bf16x8*)(ap[i] + kc * 32);
    #pragma unroll
    for (int j = 0; j < 4; ++j) {
      if (PRECONV) {
        b[j] = *(const bf16x8*)(bp[j] + kc * 32);
      } else {
        f32x4 v0 = *(const f32x4*)(bpf[j] + kc * 32);
        f32x4 v1 = *(const f32x4*)(bpf[j] + kc * 32 + 4);
        u16 h[8];
        #pragma unroll
        for (int e = 0; e < 4; ++e) { h[e] = f2bf(v0[e]); h[e + 4] = f2bf(v1[e]); }
        b[j] = *(bf16x8*)h;
      }
    }
    #pragma unroll
    for (int i = 0; i < 4; ++i)
      #pragma unroll
      for (int j = 0; j < 4; ++j)
        acc[i][j] = __builtin_amdgcn_mfma_f32_16x16x32_bf16(a[i], b[j], acc[i][j], 0, 0, 0);
  }

  #pragma unroll
  for (int i = 0; i < 4; ++i)
    #pragma unroll
    for (int j = 0; j < 4; ++j)
      #pragma unroll
      for (int rg = 0; rg < 4; ++rg) {
        int m = m0 + wm + i * 16 + kb * 4 + rg;
        int n = n0 + wn + j * 16 + fr;
        out[(size_t)m * NV + n] = acc[i][j][rg];
      }
}

extern "C" void kernel_launch(void* const* d_in, const int* in_sizes, int n_in,
                              void* d_out, int out_size, void* d_ws, size_t ws_size,
                              hipStream_t stream) {
  const int* tokens = (const int*)d_in[0];
  const float* embed = (const float*)d_in[1];
  const float* Wp = (const float*)d_in[2];
  const float* Wb = (const float*)d_in[3];
  const float* bang = (const float*)d_in[4];
  const float* agw = (const float*)d_in[5];
  const float* scales = (const float*)d_in[6];
  const float* shifts = (const float*)d_in[7];
  const float* normw = (const float*)d_in[8];
  const float* decay = (const float*)d_in[9];
  const float* gatew = (const float*)d_in[10];
  const float* onorm = (const float*)d_in[11];
  const float* lmw = (const float*)d_in[12];
  float* out = (float*)d_out;

  char* ws = (char*)d_ws;
  const size_t MB = 1u << 20;
  float* x = (float*)ws;                           // 4 MB
  u16* xh = (u16*)(ws + 4 * MB);                   // 2 MB
  u16* xl = (u16*)(ws + 6 * MB);                   // 2 MB
  float* Rf = (float*)(ws + 8 * MB);               // 4 MB
  u16* Rh = (u16*)(ws + 12 * MB);                  // 2 MB
  u16* Rl = (u16*)(ws + 14 * MB);                  // 2 MB
  u16* roth = (u16*)(ws + 16 * MB);                // 256 KB
  u16* rotl = (u16*)(ws + 16 * MB + 256 * 1024);   // 256 KB
  float* trig = (float*)(ws + 16 * MB + 512 * 1024);  // 512 B
  float* cp = (float*)(ws + 17 * MB);              // 1 MB
  float* pacc = (float*)(ws + 18 * MB);            // 2 MB
  u16* xn = (u16*)(ws + 20 * MB);                  // 2 MB
  u16* gate_h = (u16*)(ws + 22 * MB);              // 2 MB
  u16* gate_l = (u16*)(ws + 24 * MB);              // 2 MB
  u16* Wp_h = (u16*)(ws + 26 * MB);                // 7 MB
  u16* Wp_l = (u16*)(ws + 33 * MB);                // 7 MB
  u16* Wb_h = (u16*)(ws + 40 * MB);                // 7 MB
  u16* Wb_l = (u16*)(ws + 47 * MB);                // 7 MB
  u16* lm_bf = (u16*)(ws + 54 * MB);               // 311 MB (optional)

  const size_t lm_elems = (size_t)NV * D;
  bool preconv = ws_size >= 54 * MB + lm_elems * 2;

  // weight preprocessing
  k_cvt2<<<512, 256, 0, stream>>>(gatew, gate_h, gate_l, (size_t)D * D / 4);
  k_cvt2<<<1024, 256, 0, stream>>>(Wp, Wp_h, Wp_l, (size_t)NCYC * 128 * D / 4);
  k_cvt2<<<1024, 256, 0, stream>>>(Wb, Wb_h, Wb_l, (size_t)NCYC * 128 * D / 4);
  if (preconv) k_cvt<<<2048, 256, 0, stream>>>(lmw, lm_bf, lm_elems / 4);

  // cooperative persistent loop kernel (checked), fallback to multi-launch
  int occ = 0;
  hipError_t oerr = hipOccupancyMaxActiveBlocksPerMultiprocessor(&occ, (const void*)k_loop, 256, 0);
  if (oerr != hipSuccess || occ < 1) occ = 1;
  int G = occ >= 2 ? 512 : 256;
  void* kargs[] = {
      (void*)&tokens, (void*)&embed, (void*)&bang, (void*)&agw,
      (void*)&scales, (void*)&shifts, (void*)&normw, (void*)&decay, (void*)&onorm,
      (void*)&gate_h, (void*)&gate_l, (void*)&Wp_h, (void*)&Wp_l,
      (void*)&Wb_h, (void*)&Wb_l,
      (void*)&x, (void*)&xh, (void*)&xl, (void*)&Rh, (void*)&Rl, (void*)&Rf,
      (void*)&pacc, (void*)&roth, (void*)&rotl, (void*)&cp, (void*)&trig, (void*)&xn};
  hipError_t cerr = hipLaunchCooperativeKernel((const void*)k_loop, dim3(G), dim3(256),
                                               kargs, 0, stream);
  if (cerr != hipSuccess) {
    // fallback: same phases as regular launches
    fb_gather<<<256, 256, 0, stream>>>(tokens, embed, x, xh, xl, cp);
    for (int i = 0; i < NCYC; ++i) {
      const u16* Wph = Wp_h + (size_t)i * 128 * D;
      const u16* Wpl = Wp_l + (size_t)i * 128 * D;
      const u16* Wbh = Wb_h + (size_t)i * 128 * D;
      const u16* Wbl = Wb_l + (size_t)i * 128 * D;
      if ((i & 3) == 0) {
        fb_causal<<<256, 256, 0, stream>>>(x, Rh, Rl, decay);
        fb_gate<<<256, 256, 0, stream>>>(Rh, Rl, gate_h, gate_l, x, xh, xl);
      }
      fb_projang<<<128, 256, 0, stream>>>(xh, xl, Wph, Wpl, cp, agw, bang + i * 64,
                                          pacc, trig);
      fb_rot<<<16, 256, 0, stream>>>(pacc, trig, roth, rotl);
      fb_back<<<256, 256, 0, stream>>>(roth, rotl, Wbh, Wbl, Rf);
      fb_epi<<<256, 256, 0, stream>>>(x, xh, xl, Rf, scales + i * D, shifts + i * D,
                                      normw + i * D, cp);
    }
    fb_outnorm<<<256, 256, 0, stream>>>(x, onorm, xn);
  }

  if (preconv)
    k_lm<true><<<9496, 256, 0, stream>>>(xn, lm_bf, out);
  else
    k_lm<false><<<9496, 256, 0, stream>>>(xn, lmw, out);
}

// Round 10
// 3696.643 us; speedup vs baseline: 1.9273x; 1.9273x over previous
//
#include <hip/hip_runtime.h>

typedef __attribute__((ext_vector_type(4))) float f32x4;
typedef __attribute__((ext_vector_type(8))) short bf16x8;
typedef unsigned short u16;
typedef unsigned int u32;
typedef __attribute__((ext_vector_type(4))) unsigned short u16x4;

#define EPS 1.1920929e-07f
#define S 1024
#define D 1024
#define NV 151936
#define NCYC 28
#define SMEM_BYTES 49152

__device__ __forceinline__ u16 f2bf(float f) {  // RNE
  u32 u = __float_as_uint(f);
  return (u16)((u + 0x7fffu + ((u >> 16) & 1u)) >> 16);
}
__device__ __forceinline__ float bf2f(u16 h) {
  return __uint_as_float((u32)h << 16);
}
struct bfpair { u16 h, l; };
__device__ __forceinline__ bfpair split_bf(float v) {
  bfpair r;
  r.h = f2bf(v);
  r.l = f2bf(v - bf2f(r.h));
  return r;
}

__device__ __forceinline__ void gl16(const void* g, void* s) {
  __builtin_amdgcn_global_load_lds((const __attribute__((address_space(1))) u32*)g,
                                   (__attribute__((address_space(3))) u32*)s, 16, 0, 0);
}

// safe for repeated calls (sync protects sbuf reuse)
__device__ __forceinline__ float block_sum256(float v, float* sbuf) {
  #pragma unroll
  for (int off = 32; off; off >>= 1) v += __shfl_down(v, off);
  int lane = threadIdx.x & 63, w = threadIdx.x >> 6;
  __syncthreads();
  if (lane == 0) sbuf[w] = v;
  __syncthreads();
  return sbuf[0] + sbuf[1] + sbuf[2] + sbuf[3];
}

// ---------------- f32 -> bf16 (RNE) ----------------
__global__ void k_cvt(const float* __restrict__ src, u16* __restrict__ dst, size_t n4) {
  size_t i = (size_t)blockIdx.x * 256 + threadIdx.x;
  size_t stride = (size_t)gridDim.x * 256;
  for (; i < n4; i += stride) {
    f32x4 v = ((const f32x4*)src)[i];
    u16x4 o;
    #pragma unroll
    for (int e = 0; e < 4; ++e) o[e] = f2bf(v[e]);
    ((u16x4*)dst)[i] = o;
  }
}

// ---------------- f32 -> (hi, lo) bf16 split ----------------
__global__ void k_cvt2(const float* __restrict__ src, u16* __restrict__ dh,
                       u16* __restrict__ dl, size_t n4) {
  size_t i = (size_t)blockIdx.x * 256 + threadIdx.x;
  size_t stride = (size_t)gridDim.x * 256;
  for (; i < n4; i += stride) {
    f32x4 v = ((const f32x4*)src)[i];
    u16x4 oh, ol;
    #pragma unroll
    for (int e = 0; e < 4; ++e) { bfpair p = split_bf(v[e]); oh[e] = p.h; ol[e] = p.l; }
    ((u16x4*)dh)[i] = oh;
    ((u16x4*)dl)[i] = ol;
  }
}

// ================= device phases =================

// gather + initial colpart; blocks 0..255
__device__ void gather_phase(const int* tokens, const float* embed,
                             float* x, u16* xh, u16* xl, float* cp) {
  const int t = threadIdx.x;
  if (blockIdx.x >= 256) return;
  f32x4 creg = 0.f;
  for (int rr = 0; rr < 4; ++rr) {
    int s = blockIdx.x * 4 + rr;
    int tok = tokens[s];
    f32x4 v = ((const f32x4*)(embed + (size_t)tok * D))[t];
    u16x4 oh, ol;
    #pragma unroll
    for (int e = 0; e < 4; ++e) { bfpair p = split_bf(v[e]); oh[e] = p.h; ol[e] = p.l; }
    ((f32x4*)(x + (size_t)s * D))[t] = v;
    ((u16x4*)(xh + (size_t)s * D))[t] = oh;
    ((u16x4*)(xl + (size_t)s * D))[t] = ol;
    creg += v;
  }
  *(f32x4*)(cp + (size_t)blockIdx.x * D + t * 4) = creg;
}

// 64x64-tile split-bf16 GEMM over 1024xD output, 256 tiles, single-buffered (32 KB)
template <bool CADD>
__device__ void gemm64_phase(char* smem, const u16* Ah_, const u16* Al_,
                             const u16* Bh_, const u16* Bl_, int K,
                             float* xout, u16* xho, u16* xlo, float* Cout, int G) {
  const int t = threadIdx.x;
  u16* Ash = (u16*)smem;          // 4096 u16 each
  u16* Asl = Ash + 4096;
  u16* Bsh = Asl + 4096;
  u16* Bsl = Bsh + 4096;
  const int wave = t >> 6, lane = t & 63;
  const int fr = lane & 15, kb = lane >> 4;
  const int sr = t >> 3, skc = (t & 7) << 3;
  const int sswz = skc ^ ((sr & 7) << 3);
  for (int tile = blockIdx.x; tile < 256; tile += G) {
    const int m0 = (tile >> 4) * 64, n0 = (tile & 15) * 64;
    f32x4 acc[4];
    #pragma unroll
    for (int j = 0; j < 4; ++j) acc[j] = 0.f;

    for (int k0 = 0; k0 < K; k0 += 64) {
      #pragma unroll
      for (int it = 0; it < 2; ++it) {
        int r = it * 32 + sr;
        size_t ga = (size_t)(m0 + r) * K + k0 + sswz;
        size_t gb = (size_t)(n0 + r) * K + k0 + sswz;
        int so = r * 64 + skc;
        gl16(Ah_ + ga, Ash + so);
        gl16(Al_ + ga, Asl + so);
        gl16(Bh_ + gb, Bsh + so);
        gl16(Bl_ + gb, Bsl + so);
      }
      __syncthreads();
      #pragma unroll
      for (int ks = 0; ks < 2; ++ks) {
        const int cphys = (ks * 32 + kb * 8) ^ ((fr & 7) << 3);
        int oa = (wave * 16 + fr) * 64 + cphys;
        bf16x8 ah = *(const bf16x8*)&Ash[oa];
        bf16x8 al = *(const bf16x8*)&Asl[oa];
        #pragma unroll
        for (int j = 0; j < 4; ++j) {
          int ob = (j * 16 + fr) * 64 + cphys;
          bf16x8 bh = *(const bf16x8*)&Bsh[ob];
          bf16x8 bl = *(const bf16x8*)&Bsl[ob];
          acc[j] = __builtin_amdgcn_mfma_f32_16x16x32_bf16(ah, bh, acc[j], 0, 0, 0);
          acc[j] = __builtin_amdgcn_mfma_f32_16x16x32_bf16(ah, bl, acc[j], 0, 0, 0);
          acc[j] = __builtin_amdgcn_mfma_f32_16x16x32_bf16(al, bh, acc[j], 0, 0, 0);
        }
      }
      __syncthreads();
    }
    #pragma unroll
    for (int j = 0; j < 4; ++j)
      #pragma unroll
      for (int rg = 0; rg < 4; ++rg) {
        int m = m0 + wave * 16 + kb * 4 + rg;
        int n = n0 + j * 16 + fr;
        if (CADD) {
          float v = xout[(size_t)m * D + n] + acc[j][rg];
          xout[(size_t)m * D + n] = v;
          bfpair p = split_bf(v);
          xho[(size_t)m * D + n] = p.h;
          xlo[(size_t)m * D + n] = p.l;
        } else {
          Cout[(size_t)m * D + n] = acc[j][rg];
        }
      }
  }
}

// causal EMA windowed conv -> split; 256 tiles of 64x64 (40.7 KB smem)
__device__ void causal_phase(char* smem, const float* x, u16* Rh, u16* Rl,
                             float dec, int G) {
  const int t = threadIdx.x;
  for (int tile = blockIdx.x; tile < 256; tile += G) {
    int s0 = (tile >> 4) * 64, d0 = (tile & 15) * 64;
    float (*tl)[64] = (float(*)[64])smem;  // [159][64]
    for (int idx = t; idx < 159 * 64; idx += 256) {
      int rr = idx >> 6, c = idx & 63;
      int gs = s0 - 95 + rr;
      tl[rr][c] = (gs >= 0) ? x[(size_t)gs * D + d0 + c] : 0.f;
    }
    __syncthreads();
    int c = t & 63, r0 = t >> 6;
    for (int rr = r0; rr < 64; rr += 4) {
      float acc = 0.f, w = 1.f - dec;
      int base = rr + 95;
      #pragma unroll 8
      for (int j = 0; j < 96; ++j) { acc += w * tl[base - j][c]; w *= dec; }
      bfpair p = split_bf(acc);
      Rh[(size_t)(s0 + rr) * D + d0 + c] = p.h;
      Rl[(size_t)(s0 + rr) * D + d0 + c] = p.l;
    }
    __syncthreads();
  }
}

// proj GEMM, k-split x4: blocks 0..63 = (mt = b&15, kq = b>>4); 48 KB smem
__device__ void proj_phase(char* smem, const u16* xh, const u16* xl,
                           const u16* Bh_, const u16* Bl_, float* pacc) {
  const int t = threadIdx.x;
  const int mt = blockIdx.x & 15, kq = blockIdx.x >> 4;
  const int m0 = mt * 64;
  const int kbase = kq * 256;
  u16* Ash = (u16*)smem;       // 4096 u16
  u16* Asl = Ash + 4096;
  u16* Bsh = Asl + 4096;       // 8192 u16
  u16* Bsl = Bsh + 8192;
  const int wave = t >> 6, lane = t & 63;
  const int fr = lane & 15, kb = lane >> 4;
  const int sr = t >> 3, skc = (t & 7) << 3;
  const int sswz = skc ^ ((sr & 7) << 3);
  f32x4 acc[8];
  #pragma unroll
  for (int j = 0; j < 8; ++j) acc[j] = 0.f;

  for (int kt = 0; kt < 4; ++kt) {
    int k0 = kbase + kt * 64;
    #pragma unroll
    for (int it = 0; it < 2; ++it) {
      int r = it * 32 + sr;
      size_t ga = (size_t)(m0 + r) * D + k0 + sswz;
      gl16(xh + ga, Ash + r * 64 + skc);
      gl16(xl + ga, Asl + r * 64 + skc);
    }
    #pragma unroll
    for (int it = 0; it < 4; ++it) {
      int r = it * 32 + sr;
      size_t gb = (size_t)r * D + k0 + sswz;
      gl16(Bh_ + gb, Bsh + r * 64 + skc);
      gl16(Bl_ + gb, Bsl + r * 64 + skc);
    }
    __syncthreads();
    #pragma unroll
    for (int ks = 0; ks < 2; ++ks) {
      const int cphys = (ks * 32 + kb * 8) ^ ((fr & 7) << 3);
      int oa = (wave * 16 + fr) * 64 + cphys;
      bf16x8 ah = *(const bf16x8*)&Ash[oa];
      bf16x8 al = *(const bf16x8*)&Asl[oa];
      #pragma unroll
      for (int j = 0; j < 8; ++j) {
        int ob = (j * 16 + fr) * 64 + cphys;
        bf16x8 bh = *(const bf16x8*)&Bsh[ob];
        bf16x8 bl = *(const bf16x8*)&Bsl[ob];
        acc[j] = __builtin_amdgcn_mfma_f32_16x16x32_bf16(ah, bh, acc[j], 0, 0, 0);
        acc[j] = __builtin_amdgcn_mfma_f32_16x16x32_bf16(ah, bl, acc[j], 0, 0, 0);
        acc[j] = __builtin_amdgcn_mfma_f32_16x16x32_bf16(al, bh, acc[j], 0, 0, 0);
      }
    }
    __syncthreads();
  }
  float* pb = pacc + (size_t)blockIdx.x * 64 * 128;
  #pragma unroll
  for (int j = 0; j < 8; ++j)
    #pragma unroll
    for (int rg = 0; rg < 4; ++rg) {
      int ml = wave * 16 + kb * 4 + rg;
      pb[ml * 128 + j * 16 + fr] = acc[j][rg];
    }
}

// angles for plane p; fused colsum over cp[256]
__device__ void angles_phase(int p, const float* cp, const float* agw,
                             const float* bang_i, float* trig, float* sbuf) {
  const int t = threadIdx.x;
  float sum = 0.f;
  #pragma unroll
  for (int q = 0; q < 4; ++q) {
    int d = t + q * 256;
    float cs = 0.f;
    #pragma unroll 8
    for (int b = 0; b < 256; ++b) cs += cp[b * D + d];
    sum += cs * agw[p * D + d];
  }
  float total = block_sum256(sum, sbuf);
  if (t == 0) {
    float ang = bang_i[p] + 0.1f * (total * (1.f / (float)S));
    trig[p] = cosf(ang);
    trig[64 + p] = sinf(ang);
  }
}

// rot: blocks 0..15 reduce 4 k-partials + rotate -> split roth/rotl
__device__ void rot_phase(const float* pacc, const float* trig,
                          u16* roth, u16* rotl) {
  const int t = threadIdx.x;
  const int mt = blockIdx.x;
  if (mt >= 16) return;
  const int r = t >> 2, quad = t & 3;
  const int row = mt * 64 + r;
  #pragma unroll
  for (int cc = 0; cc < 4; ++cc) {
    int p = quad * 16 + cc * 4;
    f32x4 av = 0.f, bv = 0.f;
    #pragma unroll
    for (int kq = 0; kq < 4; ++kq) {
      const float* pk = pacc + ((size_t)(kq * 16 + mt) * 64 + r) * 128;
      av += *(const f32x4*)(pk + p);
      bv += *(const f32x4*)(pk + 64 + p);
    }
    f32x4 ca = *(const f32x4*)(trig + p);
    f32x4 sa = *(const f32x4*)(trig + 64 + p);
    u16x4 h0, l0, h1, l1;
    #pragma unroll
    for (int e = 0; e < 4; ++e) {
      float ra = av[e] * ca[e] - bv[e] * sa[e];
      float rb = av[e] * sa[e] + bv[e] * ca[e];
      bfpair pa = split_bf(ra);
      bfpair pb = split_bf(rb);
      h0[e] = pa.h; l0[e] = pa.l;
      h1[e] = pb.h; l1[e] = pb.l;
    }
    *(u16x4*)(roth + row * 128 + p) = h0;
    *(u16x4*)(rotl + row * 128 + p) = l0;
    *(u16x4*)(roth + row * 128 + 64 + p) = h1;
    *(u16x4*)(rotl + row * 128 + 64 + p) = l1;
  }
}

// epilogue (+ fused colpart): blocks 0..255, 4 rows each
__device__ void epilogue_phase(float* sbuf, float* x, u16* xh, u16* xl,
                               const float* Rf, const float* scale,
                               const float* shift, const float* nw, float* cp) {
  const int t = threadIdx.x;
  if (blockIdx.x >= 256) return;
  f32x4 sc = *(const f32x4*)(scale + t * 4);
  f32x4 sh = *(const f32x4*)(shift + t * 4);
  f32x4 nwv = *(const f32x4*)(nw + t * 4);
  f32x4 creg = 0.f;
  for (int rr = 0; rr < 4; ++rr) {
    int s = blockIdx.x * 4 + rr;
    f32x4 xv = *(const f32x4*)(x + (size_t)s * D + t * 4);
    f32x4 rv = *(const f32x4*)(Rf + (size_t)s * D + t * 4);
    float y[4], ss = 0.f;
    #pragma unroll
    for (int c = 0; c < 4; ++c) {
      float xr = xv[c] + rv[c];
      float tt = xr * sc[c] + sh[c];
      float act = tt / (1.f + expf(-tt));
      y[c] = act - xv[c];
      ss += y[c] * y[c];
    }
    float total = block_sum256(ss, sbuf);
    float inv = rsqrtf(total * (1.f / (float)D) + EPS);
    f32x4 o;
    u16x4 oh, ol;
    #pragma unroll
    for (int c = 0; c < 4; ++c) {
      o[c] = xv[c] + y[c] * inv * nwv[c];
      bfpair p = split_bf(o[c]);
      oh[c] = p.h;
      ol[c] = p.l;
      creg[c] += o[c];
    }
    *(f32x4*)(x + (size_t)s * D + t * 4) = o;
    *(u16x4*)(xh + (size_t)s * D + t * 4) = oh;
    *(u16x4*)(xl + (size_t)s * D + t * 4) = ol;
  }
  *(f32x4*)(cp + (size_t)blockIdx.x * D + t * 4) = creg;
}

// final rmsnorm -> bf16: blocks 0..255, 4 rows each
__device__ void outnorm_phase(float* sbuf, const float* x, const float* w, u16* xn) {
  const int t = threadIdx.x;
  if (blockIdx.x >= 256) return;
  for (int rr = 0; rr < 4; ++rr) {
    int s = blockIdx.x * 4 + rr;
    f32x4 xv = *(const f32x4*)(x + (size_t)s * D + t * 4);
    float total = block_sum256(xv[0]*xv[0] + xv[1]*xv[1] + xv[2]*xv[2] + xv[3]*xv[3], sbuf);
    float inv = rsqrtf(total * (1.f / (float)D) + EPS);
    f32x4 wv = *(const f32x4*)(w + t * 4);
    u16x4 o;
    #pragma unroll
    for (int c = 0; c < 4; ++c) o[c] = f2bf(xv[c] * inv * wv[c]);
    *(u16x4*)(xn + (size_t)s * D + t * 4) = o;
  }
}

// ================= kernel wrappers =================
__global__ __launch_bounds__(256) void fb_gather(const int* tokens, const float* embed,
                                                 float* x, u16* xh, u16* xl, float* cp) {
  gather_phase(tokens, embed, x, xh, xl, cp);
}
__global__ __launch_bounds__(256) void fb_causal(const float* x, u16* Rh, u16* Rl,
                                                 const float* decay) {
  __shared__ __align__(16) char sm[40704];
  causal_phase(sm, x, Rh, Rl, 1.f / (1.f + expf(-decay[0])), gridDim.x);
}
__global__ __launch_bounds__(256) void fb_gate(const u16* Rh, const u16* Rl,
                                               const u16* gh, const u16* gl,
                                               float* x, u16* xh, u16* xl) {
  __shared__ __align__(16) char sm[32768];
  gemm64_phase<true>(sm, Rh, Rl, gh, gl, 1024, x, xh, xl, nullptr, gridDim.x);
}
__global__ __launch_bounds__(256) void fb_projang(const u16* xh, const u16* xl,
                                                  const u16* Wph, const u16* Wpl,
                                                  const float* cp, const float* agw,
                                                  const float* bang_i,
                                                  float* pacc, float* trig) {
  __shared__ __align__(16) char sm[SMEM_BYTES];
  __shared__ float sbuf[4];
  if (blockIdx.x < 64) proj_phase(sm, xh, xl, Wph, Wpl, pacc);
  else angles_phase(blockIdx.x - 64, cp, agw, bang_i, trig, sbuf);
}
__global__ __launch_bounds__(256) void fb_rot(const float* pacc, const float* trig,
                                              u16* roth, u16* rotl) {
  rot_phase(pacc, trig, roth, rotl);
}
__global__ __launch_bounds__(256) void fb_back(const u16* roth, const u16* rotl,
                                               const u16* Wbh, const u16* Wbl, float* Rf) {
  __shared__ __align__(16) char sm[32768];
  gemm64_phase<false>(sm, roth, rotl, Wbh, Wbl, 128, nullptr, nullptr, nullptr, Rf, gridDim.x);
}
__global__ __launch_bounds__(256) void fb_epi(float* x, u16* xh, u16* xl, const float* Rf,
                                              const float* scale, const float* shift,
                                              const float* nw, float* cp) {
  __shared__ float sbuf[4];
  epilogue_phase(sbuf, x, xh, xl, Rf, scale, shift, nw, cp);
}
__global__ __launch_bounds__(256) void fb_outnorm(const float* x, const float* w, u16* xn) {
  __shared__ float sbuf[4];
  outnorm_phase(sbuf, x, w, xn);
}

// ---------------- lm_head GEMM: no-LDS direct-to-register, XCD-chunk swizzle -------
template <bool PRECONV>
__global__ __launch_bounds__(256) void k_lm(const u16* __restrict__ A,
                                            const void* __restrict__ Wsrc,
                                            float* __restrict__ out) {
  const int bid = blockIdx.x;
  const int lid = (bid & 7) * 1187 + (bid >> 3);  // bijective: 9496 = 8*1187
  const int m0 = (lid & 7) * 128;
  const int n0 = (lid >> 3) * 128;
  const int t = threadIdx.x;
  const int wave = t >> 6, lane = t & 63;
  const int wm = (wave >> 1) * 64, wn = (wave & 1) * 64;
  const int fr = lane & 15, kb = lane >> 4;
  const u16* Wb16 = (const u16*)Wsrc;
  const float* Wf = (const float*)Wsrc;

  const u16* ap[4];
  const u16* bp[4];
  const float* bpf[4];
  #pragma unroll
  for (int i = 0; i < 4; ++i)
    ap[i] = A + (size_t)(m0 + wm + i * 16 + fr) * D + kb * 8;
  #pragma unroll
  for (int j = 0; j < 4; ++j) {
    int n = n0 + wn + j * 16 + fr;
    if (PRECONV) bp[j] = Wb16 + (size_t)n * D + kb * 8;
    else bpf[j] = Wf + (size_t)n * D + kb * 8;
  }

  f32x4 acc[4][4];
  #pragma unroll
  for (int i = 0; i < 4; ++i)
    #pragma unroll
    for (int j = 0; j < 4; ++j) acc[i][j] = 0.f;

  #pragma unroll 4
  for (int kc = 0; kc < 32; ++kc) {
    bf16x8 a[4], b[4];
    #pragma unroll
    for (int i = 0; i < 4; ++i) a[i] = *(const bf16x8*)(ap[i] + kc * 32);
    #pragma unroll
    for (int j = 0; j < 4; ++j) {
      if (PRECONV) {
        b[j] = *(const bf16x8*)(bp[j] + kc * 32);
      } else {
        f32x4 v0 = *(const f32x4*)(bpf[j] + kc * 32);
        f32x4 v1 = *(const f32x4*)(bpf[j] + kc * 32 + 4);
        u16 h[8];
        #pragma unroll
        for (int e = 0; e < 4; ++e) { h[e] = f2bf(v0[e]); h[e + 4] = f2bf(v1[e]); }
        b[j] = *(bf16x8*)h;
      }
    }
    #pragma unroll
    for (int i = 0; i < 4; ++i)
      #pragma unroll
      for (int j = 0; j < 4; ++j)
        acc[i][j] = __builtin_amdgcn_mfma_f32_16x16x32_bf16(a[i], b[j], acc[i][j], 0, 0, 0);
  }

  #pragma unroll
  for (int i = 0; i < 4; ++i)
    #pragma unroll
    for (int j = 0; j < 4; ++j)
      #pragma unroll
      for (int rg = 0; rg < 4; ++rg) {
        int m = m0 + wm + i * 16 + kb * 4 + rg;
        int n = n0 + wn + j * 16 + fr;
        out[(size_t)m * NV + n] = acc[i][j][rg];
      }
}

extern "C" void kernel_launch(void* const* d_in, const int* in_sizes, int n_in,
                              void* d_out, int out_size, void* d_ws, size_t ws_size,
                              hipStream_t stream) {
  const int* tokens = (const int*)d_in[0];
  const float* embed = (const float*)d_in[1];
  const float* Wp = (const float*)d_in[2];
  const float* Wb = (const float*)d_in[3];
  const float* bang = (const float*)d_in[4];
  const float* agw = (const float*)d_in[5];
  const float* scales = (const float*)d_in[6];
  const float* shifts = (const float*)d_in[7];
  const float* normw = (const float*)d_in[8];
  const float* decay = (const float*)d_in[9];
  const float* gatew = (const float*)d_in[10];
  const float* onorm = (const float*)d_in[11];
  const float* lmw = (const float*)d_in[12];
  float* out = (float*)d_out;

  char* ws = (char*)d_ws;
  const size_t MB = 1u << 20;
  float* x = (float*)ws;                           // 4 MB
  u16* xh = (u16*)(ws + 4 * MB);                   // 2 MB
  u16* xl = (u16*)(ws + 6 * MB);                   // 2 MB
  float* Rf = (float*)(ws + 8 * MB);               // 4 MB
  u16* Rh = (u16*)(ws + 12 * MB);                  // 2 MB
  u16* Rl = (u16*)(ws + 14 * MB);                  // 2 MB
  u16* roth = (u16*)(ws + 16 * MB);                // 256 KB
  u16* rotl = (u16*)(ws + 16 * MB + 256 * 1024);   // 256 KB
  float* trig = (float*)(ws + 16 * MB + 512 * 1024);  // 512 B
  float* cp = (float*)(ws + 17 * MB);              // 1 MB
  float* pacc = (float*)(ws + 18 * MB);            // 2 MB
  u16* xn = (u16*)(ws + 20 * MB);                  // 2 MB
  u16* gate_h = (u16*)(ws + 22 * MB);              // 2 MB
  u16* gate_l = (u16*)(ws + 24 * MB);              // 2 MB
  u16* Wp_h = (u16*)(ws + 26 * MB);                // 7 MB
  u16* Wp_l = (u16*)(ws + 33 * MB);                // 7 MB
  u16* Wb_h = (u16*)(ws + 40 * MB);                // 7 MB
  u16* Wb_l = (u16*)(ws + 47 * MB);                // 7 MB
  u16* lm_bf = (u16*)(ws + 54 * MB);               // 311 MB (optional)

  const size_t lm_elems = (size_t)NV * D;
  bool preconv = ws_size >= 54 * MB + lm_elems * 2;

  // weight preprocessing
  k_cvt2<<<512, 256, 0, stream>>>(gatew, gate_h, gate_l, (size_t)D * D / 4);
  k_cvt2<<<1024, 256, 0, stream>>>(Wp, Wp_h, Wp_l, (size_t)NCYC * 128 * D / 4);
  k_cvt2<<<1024, 256, 0, stream>>>(Wb, Wb_h, Wb_l, (size_t)NCYC * 128 * D / 4);
  if (preconv) k_cvt<<<2048, 256, 0, stream>>>(lmw, lm_bf, lm_elems / 4);

  fb_gather<<<256, 256, 0, stream>>>(tokens, embed, x, xh, xl, cp);
  for (int i = 0; i < NCYC; ++i) {
    const u16* Wph = Wp_h + (size_t)i * 128 * D;
    const u16* Wpl = Wp_l + (size_t)i * 128 * D;
    const u16* Wbh = Wb_h + (size_t)i * 128 * D;
    const u16* Wbl = Wb_l + (size_t)i * 128 * D;
    if ((i & 3) == 0) {
      fb_causal<<<256, 256, 0, stream>>>(x, Rh, Rl, decay);
      fb_gate<<<256, 256, 0, stream>>>(Rh, Rl, gate_h, gate_l, x, xh, xl);
    }
    fb_projang<<<128, 256, 0, stream>>>(xh, xl, Wph, Wpl, cp, agw, bang + i * 64,
                                        pacc, trig);
    fb_rot<<<16, 256, 0, stream>>>(pacc, trig, roth, rotl);
    fb_back<<<256, 256, 0, stream>>>(roth, rotl, Wbh, Wbl, Rf);
    fb_epi<<<256, 256, 0, stream>>>(x, xh, xl, Rf, scales + i * D, shifts + i * D,
                                    normw + i * D, cp);
  }
  fb_outnorm<<<256, 256, 0, stream>>>(x, onorm, xn);

  if (preconv)
    k_lm<true><<<9496, 256, 0, stream>>>(xn, lm_bf, out);
  else
    k_lm<false><<<9496, 256, 0, stream>>>(xn, lmw, out);
}

// Round 12
// 2985.232 us; speedup vs baseline: 2.3866x; 1.2383x over previous
//
#include <hip/hip_runtime.h>

typedef __attribute__((ext_vector_type(4))) float f32x4;
typedef __attribute__((ext_vector_type(8))) short bf16x8;
typedef unsigned short u16;
typedef unsigned int u32;
typedef __attribute__((ext_vector_type(4))) unsigned short u16x4;

#define EPS 1.1920929e-07f
#define S 1024
#define D 1024
#define NV 151936
#define NCYC 28
#define SMEM_BYTES 49152

__device__ __forceinline__ u16 f2bf(float f) {  // RNE
  u32 u = __float_as_uint(f);
  return (u16)((u + 0x7fffu + ((u >> 16) & 1u)) >> 16);
}
__device__ __forceinline__ float bf2f(u16 h) {
  return __uint_as_float((u32)h << 16);
}
struct bfpair { u16 h, l; };
__device__ __forceinline__ bfpair split_bf(float v) {
  bfpair r;
  r.h = f2bf(v);
  r.l = f2bf(v - bf2f(r.h));
  return r;
}

__device__ __forceinline__ void gl16(const void* g, void* s) {
  __builtin_amdgcn_global_load_lds((const __attribute__((address_space(1))) u32*)g,
                                   (__attribute__((address_space(3))) u32*)s, 16, 0, 0);
}

// safe for repeated calls (sync protects sbuf reuse)
__device__ __forceinline__ float block_sum256(float v, float* sbuf) {
  #pragma unroll
  for (int off = 32; off; off >>= 1) v += __shfl_down(v, off);
  int lane = threadIdx.x & 63, w = threadIdx.x >> 6;
  __syncthreads();
  if (lane == 0) sbuf[w] = v;
  __syncthreads();
  return sbuf[0] + sbuf[1] + sbuf[2] + sbuf[3];
}

// ---------------- f32 -> bf16 (RNE) ----------------
__global__ void k_cvt(const float* __restrict__ src, u16* __restrict__ dst, size_t n4) {
  size_t i = (size_t)blockIdx.x * 256 + threadIdx.x;
  size_t stride = (size_t)gridDim.x * 256;
  for (; i < n4; i += stride) {
    f32x4 v = ((const f32x4*)src)[i];
    u16x4 o;
    #pragma unroll
    for (int e = 0; e < 4; ++e) o[e] = f2bf(v[e]);
    ((u16x4*)dst)[i] = o;
  }
}

// ---------------- f32 -> (hi, lo) bf16 split ----------------
__global__ void k_cvt2(const float* __restrict__ src, u16* __restrict__ dh,
                       u16* __restrict__ dl, size_t n4) {
  size_t i = (size_t)blockIdx.x * 256 + threadIdx.x;
  size_t stride = (size_t)gridDim.x * 256;
  for (; i < n4; i += stride) {
    f32x4 v = ((const f32x4*)src)[i];
    u16x4 oh, ol;
    #pragma unroll
    for (int e = 0; e < 4; ++e) { bfpair p = split_bf(v[e]); oh[e] = p.h; ol[e] = p.l; }
    ((u16x4*)dh)[i] = oh;
    ((u16x4*)dl)[i] = ol;
  }
}

// ================= device phases =================

// gather + initial colpart; blocks 0..255
__device__ void gather_phase(const int* tokens, const float* embed,
                             float* x, u16* xh, u16* xl, float* cp) {
  const int t = threadIdx.x;
  if (blockIdx.x >= 256) return;
  f32x4 creg = 0.f;
  for (int rr = 0; rr < 4; ++rr) {
    int s = blockIdx.x * 4 + rr;
    int tok = tokens[s];
    f32x4 v = ((const f32x4*)(embed + (size_t)tok * D))[t];
    u16x4 oh, ol;
    #pragma unroll
    for (int e = 0; e < 4; ++e) { bfpair p = split_bf(v[e]); oh[e] = p.h; ol[e] = p.l; }
    ((f32x4*)(x + (size_t)s * D))[t] = v;
    ((u16x4*)(xh + (size_t)s * D))[t] = oh;
    ((u16x4*)(xl + (size_t)s * D))[t] = ol;
    creg += v;
  }
  *(f32x4*)(cp + (size_t)blockIdx.x * D + t * 4) = creg;
}

// 64x64-tile split-bf16 GEMM over 1024xD output, 256 tiles, single-buffered (32 KB)
template <bool CADD>
__device__ void gemm64_phase(char* smem, const u16* Ah_, const u16* Al_,
                             const u16* Bh_, const u16* Bl_, int K,
                             float* xout, u16* xho, u16* xlo, float* Cout, int G) {
  const int t = threadIdx.x;
  u16* Ash = (u16*)smem;          // 4096 u16 each
  u16* Asl = Ash + 4096;
  u16* Bsh = Asl + 4096;
  u16* Bsl = Bsh + 4096;
  const int wave = t >> 6, lane = t & 63;
  const int fr = lane & 15, kb = lane >> 4;
  const int sr = t >> 3, skc = (t & 7) << 3;
  const int sswz = skc ^ ((sr & 7) << 3);
  for (int tile = blockIdx.x; tile < 256; tile += G) {
    const int m0 = (tile >> 4) * 64, n0 = (tile & 15) * 64;
    f32x4 acc[4];
    #pragma unroll
    for (int j = 0; j < 4; ++j) acc[j] = 0.f;

    for (int k0 = 0; k0 < K; k0 += 64) {
      #pragma unroll
      for (int it = 0; it < 2; ++it) {
        int r = it * 32 + sr;
        size_t ga = (size_t)(m0 + r) * K + k0 + sswz;
        size_t gb = (size_t)(n0 + r) * K + k0 + sswz;
        int so = r * 64 + skc;
        gl16(Ah_ + ga, Ash + so);
        gl16(Al_ + ga, Asl + so);
        gl16(Bh_ + gb, Bsh + so);
        gl16(Bl_ + gb, Bsl + so);
      }
      __syncthreads();
      #pragma unroll
      for (int ks = 0; ks < 2; ++ks) {
        const int cphys = (ks * 32 + kb * 8) ^ ((fr & 7) << 3);
        int oa = (wave * 16 + fr) * 64 + cphys;
        bf16x8 ah = *(const bf16x8*)&Ash[oa];
        bf16x8 al = *(const bf16x8*)&Asl[oa];
        #pragma unroll
        for (int j = 0; j < 4; ++j) {
          int ob = (j * 16 + fr) * 64 + cphys;
          bf16x8 bh = *(const bf16x8*)&Bsh[ob];
          bf16x8 bl = *(const bf16x8*)&Bsl[ob];
          acc[j] = __builtin_amdgcn_mfma_f32_16x16x32_bf16(ah, bh, acc[j], 0, 0, 0);
          acc[j] = __builtin_amdgcn_mfma_f32_16x16x32_bf16(ah, bl, acc[j], 0, 0, 0);
          acc[j] = __builtin_amdgcn_mfma_f32_16x16x32_bf16(al, bh, acc[j], 0, 0, 0);
        }
      }
      __syncthreads();
    }
    #pragma unroll
    for (int j = 0; j < 4; ++j)
      #pragma unroll
      for (int rg = 0; rg < 4; ++rg) {
        int m = m0 + wave * 16 + kb * 4 + rg;
        int n = n0 + j * 16 + fr;
        if (CADD) {
          float v = xout[(size_t)m * D + n] + acc[j][rg];
          xout[(size_t)m * D + n] = v;
          bfpair p = split_bf(v);
          xho[(size_t)m * D + n] = p.h;
          xlo[(size_t)m * D + n] = p.l;
        } else {
          Cout[(size_t)m * D + n] = acc[j][rg];
        }
      }
  }
}

// causal EMA windowed conv -> split; 256 tiles of 64x64 (40.7 KB smem)
__device__ void causal_phase(char* smem, const float* x, u16* Rh, u16* Rl,
                             float dec, int G) {
  const int t = threadIdx.x;
  for (int tile = blockIdx.x; tile < 256; tile += G) {
    int s0 = (tile >> 4) * 64, d0 = (tile & 15) * 64;
    float (*tl)[64] = (float(*)[64])smem;  // [159][64]
    for (int idx = t; idx < 159 * 64; idx += 256) {
      int rr = idx >> 6, c = idx & 63;
      int gs = s0 - 95 + rr;
      tl[rr][c] = (gs >= 0) ? x[(size_t)gs * D + d0 + c] : 0.f;
    }
    __syncthreads();
    int c = t & 63, r0 = t >> 6;
    for (int rr = r0; rr < 64; rr += 4) {
      float acc = 0.f, w = 1.f - dec;
      int base = rr + 95;
      #pragma unroll 8
      for (int j = 0; j < 96; ++j) { acc += w * tl[base - j][c]; w *= dec; }
      bfpair p = split_bf(acc);
      Rh[(size_t)(s0 + rr) * D + d0 + c] = p.h;
      Rl[(size_t)(s0 + rr) * D + d0 + c] = p.l;
    }
    __syncthreads();
  }
}

// proj GEMM, k-split x4: blocks 0..63 = (mt = b&15, kq = b>>4); 48 KB smem
__device__ void proj_phase(char* smem, const u16* xh, const u16* xl,
                           const u16* Bh_, const u16* Bl_, float* pacc) {
  const int t = threadIdx.x;
  const int mt = blockIdx.x & 15, kq = blockIdx.x >> 4;
  const int m0 = mt * 64;
  const int kbase = kq * 256;
  u16* Ash = (u16*)smem;       // 4096 u16
  u16* Asl = Ash + 4096;
  u16* Bsh = Asl + 4096;       // 8192 u16
  u16* Bsl = Bsh + 8192;
  const int wave = t >> 6, lane = t & 63;
  const int fr = lane & 15, kb = lane >> 4;
  const int sr = t >> 3, skc = (t & 7) << 3;
  const int sswz = skc ^ ((sr & 7) << 3);
  f32x4 acc[8];
  #pragma unroll
  for (int j = 0; j < 8; ++j) acc[j] = 0.f;

  for (int kt = 0; kt < 4; ++kt) {
    int k0 = kbase + kt * 64;
    #pragma unroll
    for (int it = 0; it < 2; ++it) {
      int r = it * 32 + sr;
      size_t ga = (size_t)(m0 + r) * D + k0 + sswz;
      gl16(xh + ga, Ash + r * 64 + skc);
      gl16(xl + ga, Asl + r * 64 + skc);
    }
    #pragma unroll
    for (int it = 0; it < 4; ++it) {
      int r = it * 32 + sr;
      size_t gb = (size_t)r * D + k0 + sswz;
      gl16(Bh_ + gb, Bsh + r * 64 + skc);
      gl16(Bl_ + gb, Bsl + r * 64 + skc);
    }
    __syncthreads();
    #pragma unroll
    for (int ks = 0; ks < 2; ++ks) {
      const int cphys = (ks * 32 + kb * 8) ^ ((fr & 7) << 3);
      int oa = (wave * 16 + fr) * 64 + cphys;
      bf16x8 ah = *(const bf16x8*)&Ash[oa];
      bf16x8 al = *(const bf16x8*)&Asl[oa];
      #pragma unroll
      for (int j = 0; j < 8; ++j) {
        int ob = (j * 16 + fr) * 64 + cphys;
        bf16x8 bh = *(const bf16x8*)&Bsh[ob];
        bf16x8 bl = *(const bf16x8*)&Bsl[ob];
        acc[j] = __builtin_amdgcn_mfma_f32_16x16x32_bf16(ah, bh, acc[j], 0, 0, 0);
        acc[j] = __builtin_amdgcn_mfma_f32_16x16x32_bf16(ah, bl, acc[j], 0, 0, 0);
        acc[j] = __builtin_amdgcn_mfma_f32_16x16x32_bf16(al, bh, acc[j], 0, 0, 0);
      }
    }
    __syncthreads();
  }
  float* pb = pacc + (size_t)blockIdx.x * 64 * 128;
  #pragma unroll
  for (int j = 0; j < 8; ++j)
    #pragma unroll
    for (int rg = 0; rg < 4; ++rg) {
      int ml = wave * 16 + kb * 4 + rg;
      pb[ml * 128 + j * 16 + fr] = acc[j][rg];
    }
}

// angles for plane p; fused colsum over cp[256]
__device__ void angles_phase(int p, const float* cp, const float* agw,
                             const float* bang_i, float* trig, float* sbuf) {
  const int t = threadIdx.x;
  float sum = 0.f;
  #pragma unroll
  for (int q = 0; q < 4; ++q) {
    int d = t + q * 256;
    float cs = 0.f;
    #pragma unroll 8
    for (int b = 0; b < 256; ++b) cs += cp[b * D + d];
    sum += cs * agw[p * D + d];
  }
  float total = block_sum256(sum, sbuf);
  if (t == 0) {
    float ang = bang_i[p] + 0.1f * (total * (1.f / (float)S));
    trig[p] = cosf(ang);
    trig[64 + p] = sinf(ang);
  }
}

// epilogue (+ fused colpart): blocks 0..255, 4 rows each
__device__ void epilogue_phase(float* sbuf, float* x, u16* xh, u16* xl,
                               const float* Rf, const float* scale,
                               const float* shift, const float* nw, float* cp) {
  const int t = threadIdx.x;
  if (blockIdx.x >= 256) return;
  f32x4 sc = *(const f32x4*)(scale + t * 4);
  f32x4 sh = *(const f32x4*)(shift + t * 4);
  f32x4 nwv = *(const f32x4*)(nw + t * 4);
  f32x4 creg = 0.f;
  for (int rr = 0; rr < 4; ++rr) {
    int s = blockIdx.x * 4 + rr;
    f32x4 xv = *(const f32x4*)(x + (size_t)s * D + t * 4);
    f32x4 rv = *(const f32x4*)(Rf + (size_t)s * D + t * 4);
    float y[4], ss = 0.f;
    #pragma unroll
    for (int c = 0; c < 4; ++c) {
      float xr = xv[c] + rv[c];
      float tt = xr * sc[c] + sh[c];
      float act = tt / (1.f + expf(-tt));
      y[c] = act - xv[c];
      ss += y[c] * y[c];
    }
    float total = block_sum256(ss, sbuf);
    float inv = rsqrtf(total * (1.f / (float)D) + EPS);
    f32x4 o;
    u16x4 oh, ol;
    #pragma unroll
    for (int c = 0; c < 4; ++c) {
      o[c] = xv[c] + y[c] * inv * nwv[c];
      bfpair p = split_bf(o[c]);
      oh[c] = p.h;
      ol[c] = p.l;
      creg[c] += o[c];
    }
    *(f32x4*)(x + (size_t)s * D + t * 4) = o;
    *(u16x4*)(xh + (size_t)s * D + t * 4) = oh;
    *(u16x4*)(xl + (size_t)s * D + t * 4) = ol;
  }
  *(f32x4*)(cp + (size_t)blockIdx.x * D + t * 4) = creg;
}

// final rmsnorm -> bf16: blocks 0..255, 4 rows each
__device__ void outnorm_phase(float* sbuf, const float* x, const float* w, u16* xn) {
  const int t = threadIdx.x;
  if (blockIdx.x >= 256) return;
  for (int rr = 0; rr < 4; ++rr) {
    int s = blockIdx.x * 4 + rr;
    f32x4 xv = *(const f32x4*)(x + (size_t)s * D + t * 4);
    float total = block_sum256(xv[0]*xv[0] + xv[1]*xv[1] + xv[2]*xv[2] + xv[3]*xv[3], sbuf);
    float inv = rsqrtf(total * (1.f / (float)D) + EPS);
    f32x4 wv = *(const f32x4*)(w + t * 4);
    u16x4 o;
    #pragma unroll
    for (int c = 0; c < 4; ++c) o[c] = f2bf(xv[c] * inv * wv[c]);
    *(u16x4*)(xn + (size_t)s * D + t * 4) = o;
  }
}

// ================= kernel wrappers =================
__global__ __launch_bounds__(256) void fb_gather(const int* tokens, const float* embed,
                                                 float* x, u16* xh, u16* xl, float* cp) {
  gather_phase(tokens, embed, x, xh, xl, cp);
}
__global__ __launch_bounds__(256) void fb_causal(const float* x, u16* Rh, u16* Rl,
                                                 const float* decay) {
  __shared__ __align__(16) char sm[40704];
  causal_phase(sm, x, Rh, Rl, 1.f / (1.f + expf(-decay[0])), gridDim.x);
}
__global__ __launch_bounds__(256) void fb_gate(const u16* Rh, const u16* Rl,
                                               const u16* gh, const u16* gl,
                                               float* x, u16* xh, u16* xl) {
  __shared__ __align__(16) char sm[32768];
  gemm64_phase<true>(sm, Rh, Rl, gh, gl, 1024, x, xh, xl, nullptr, gridDim.x);
}
__global__ __launch_bounds__(256) void fb_projang(const u16* xh, const u16* xl,
                                                  const u16* Wph, const u16* Wpl,
                                                  const float* cp, const float* agw,
                                                  const float* bang_i,
                                                  float* pacc, float* trig) {
  __shared__ __align__(16) char sm[SMEM_BYTES];
  __shared__ float sbuf[4];
  if (blockIdx.x < 64) proj_phase(sm, xh, xl, Wph, Wpl, pacc);
  else angles_phase(blockIdx.x - 64, cp, agw, bang_i, trig, sbuf);
}

// back GEMM with FUSED rotation: A-tile (64x128 rot) computed from pacc+trig into LDS.
// LDS convention (matches gemm64): phys_slot = logical_col ^ ((row&7)<<3).
__global__ __launch_bounds__(256) void fb_back(const float* __restrict__ pacc,
                                               const float* __restrict__ trig,
                                               const u16* __restrict__ Bh_,
                                               const u16* __restrict__ Bl_,
                                               float* __restrict__ Rf) {
  __shared__ u16 Ash[64 * 128];   // 16 KB
  __shared__ u16 Asl[64 * 128];   // 16 KB
  __shared__ u16 Bsh[64 * 64];    // 8 KB
  __shared__ u16 Bsl[64 * 64];    // 8 KB
  const int t = threadIdx.x;
  const int tile = blockIdx.x;
  const int mt = tile >> 4;
  const int m0 = mt * 64, n0 = (tile & 15) * 64;
  const int wave = t >> 6, lane = t & 63;
  const int fr = lane & 15, kb = lane >> 4;
  const int sr = t >> 3, skc = (t & 7) << 3;
  const int sswz = skc ^ ((sr & 7) << 3);

  // ---- build rotated A tile: LOAD logical cols skc..skc+7, STORE at swizzled slot --
  #pragma unroll
  for (int ri = 0; ri < 2; ++ri) {
    int r = ri * 32 + sr;
    int pdst = skc ^ ((r & 7) << 3);  // physical slot for logical block skc
    f32x4 a0 = 0.f, a1 = 0.f, b0 = 0.f, b1 = 0.f;
    #pragma unroll
    for (int kq = 0; kq < 4; ++kq) {
      const float* pk = pacc + ((size_t)(kq * 16 + mt) * 64 + r) * 128;
      a0 += *(const f32x4*)(pk + skc);
      a1 += *(const f32x4*)(pk + skc + 4);
      b0 += *(const f32x4*)(pk + 64 + skc);
      b1 += *(const f32x4*)(pk + 64 + skc + 4);
    }
    #pragma unroll
    for (int kh = 0; kh < 2; ++kh) {
      u16 hbuf[8], lbuf[8];
      #pragma unroll
      for (int j = 0; j < 8; ++j) {
        float av = (j < 4) ? a0[j & 3] : a1[j & 3];
        float bv = (j < 4) ? b0[j & 3] : b1[j & 3];
        float ca = trig[skc + j], sa = trig[64 + skc + j];
        float v = (kh == 0) ? (av * ca - bv * sa) : (av * sa + bv * ca);
        bfpair p = split_bf(v);
        hbuf[j] = p.h;
        lbuf[j] = p.l;
      }
      int so = r * 128 + kh * 64 + pdst;
      *(bf16x8*)&Ash[so] = *(bf16x8*)hbuf;
      *(bf16x8*)&Asl[so] = *(bf16x8*)lbuf;
    }
  }
  __syncthreads();

  f32x4 acc[4];
  #pragma unroll
  for (int j = 0; j < 4; ++j) acc[j] = 0.f;

  for (int kt = 0; kt < 2; ++kt) {
    int k0 = kt * 64;
    #pragma unroll
    for (int it = 0; it < 2; ++it) {
      int r = it * 32 + sr;
      size_t gb = (size_t)(n0 + r) * 128 + k0 + sswz;
      gl16(Bh_ + gb, Bsh + r * 64 + skc);
      gl16(Bl_ + gb, Bsl + r * 64 + skc);
    }
    __syncthreads();
    #pragma unroll
    for (int ks = 0; ks < 2; ++ks) {
      const int w = (ks * 32 + kb * 8) ^ ((fr & 7) << 3);
      int oa = (wave * 16 + fr) * 128 + k0 + w;
      bf16x8 ah = *(const bf16x8*)&Ash[oa];
      bf16x8 al = *(const bf16x8*)&Asl[oa];
      #pragma unroll
      for (int j = 0; j < 4; ++j) {
        int ob = (j * 16 + fr) * 64 + w;
        bf16x8 bh = *(const bf16x8*)&Bsh[ob];
        bf16x8 bl = *(const bf16x8*)&Bsl[ob];
        acc[j] = __builtin_amdgcn_mfma_f32_16x16x32_bf16(ah, bh, acc[j], 0, 0, 0);
        acc[j] = __builtin_amdgcn_mfma_f32_16x16x32_bf16(ah, bl, acc[j], 0, 0, 0);
        acc[j] = __builtin_amdgcn_mfma_f32_16x16x32_bf16(al, bh, acc[j], 0, 0, 0);
      }
    }
    __syncthreads();
  }
  #pragma unroll
  for (int j = 0; j < 4; ++j)
    #pragma unroll
    for (int rg = 0; rg < 4; ++rg) {
      int m = m0 + wave * 16 + kb * 4 + rg;
      int n = n0 + j * 16 + fr;
      Rf[(size_t)m * D + n] = acc[j][rg];
    }
}

__global__ __launch_bounds__(256) void fb_epi(float* x, u16* xh, u16* xl, const float* Rf,
                                              const float* scale, const float* shift,
                                              const float* nw, float* cp) {
  __shared__ float sbuf[4];
  epilogue_phase(sbuf, x, xh, xl, Rf, scale, shift, nw, cp);
}
__global__ __launch_bounds__(256) void fb_outnorm(const float* x, const float* w, u16* xn) {
  __shared__ float sbuf[4];
  outnorm_phase(sbuf, x, w, xn);
}

// ---------------- lm_head GEMM, m97-style LDS + T2 swizzle, XCD-chunk swizzle ------
// grid: 9496 = 8 m-tiles x 1187 n-tiles (1-D).
template <bool PRECONV>
__global__ __launch_bounds__(256) void k_lm(const u16* __restrict__ A,
                                            const void* __restrict__ Wsrc,
                                            float* __restrict__ out) {
  __shared__ u16 As[128 * 64];
  __shared__ u16 Bs[128 * 64];
  const int bid = blockIdx.x;
  const int lid = (bid & 7) * 1187 + (bid >> 3);  // bijective: 9496 = 8*1187
  const int m0 = (lid & 7) * 128;
  const int n0 = (lid >> 3) * 128;
  const int t = threadIdx.x;
  const int wave = t >> 6, lane = t & 63;
  const int wm = (wave >> 1) * 64, wn = (wave & 1) * 64;
  const int fr = lane & 15, kb = lane >> 4;
  const int sr = t >> 3, skc = (t & 7) << 3;
  const int sswz = skc ^ ((sr & 7) << 3);
  const u16* Wb16 = (const u16*)Wsrc;
  const float* Wf = (const float*)Wsrc;
  f32x4 acc[4][4];
  #pragma unroll
  for (int i = 0; i < 4; ++i)
    #pragma unroll
    for (int j = 0; j < 4; ++j) acc[i][j] = 0.f;

  for (int k0 = 0; k0 < D; k0 += 64) {
    #pragma unroll
    for (int it = 0; it < 4; ++it) {
      int r = it * 32 + sr;
      gl16(A + (size_t)(m0 + r) * D + k0 + sswz, As + r * 64 + skc);
    }
    if (PRECONV) {
      #pragma unroll
      for (int it = 0; it < 4; ++it) {
        int r = it * 32 + sr;
        gl16(Wb16 + (size_t)(n0 + r) * D + k0 + sswz, Bs + r * 64 + skc);
      }
    } else {
      #pragma unroll
      for (int it = 0; it < 4; ++it) {
        int r = it * 32 + sr;
        const float* src = Wf + (size_t)(n0 + r) * D + k0 + sswz;
        f32x4 v0 = *(const f32x4*)src;
        f32x4 v1 = *(const f32x4*)(src + 4);
        u16 h[8];
        #pragma unroll
        for (int e = 0; e < 4; ++e) { h[e] = f2bf(v0[e]); h[e + 4] = f2bf(v1[e]); }
        *(bf16x8*)&Bs[r * 64 + skc] = *(bf16x8*)h;
      }
    }
    __syncthreads();
    #pragma unroll
    for (int ks = 0; ks < 2; ++ks) {
      const int cphys = (ks * 32 + kb * 8) ^ ((fr & 7) << 3);
      bf16x8 a[4], b[4];
      #pragma unroll
      for (int i = 0; i < 4; ++i) a[i] = *(const bf16x8*)&As[(wm + i * 16 + fr) * 64 + cphys];
      #pragma unroll
      for (int j = 0; j < 4; ++j) b[j] = *(const bf16x8*)&Bs[(wn + j * 16 + fr) * 64 + cphys];
      #pragma unroll
      for (int i = 0; i < 4; ++i)
        #pragma unroll
        for (int j = 0; j < 4; ++j)
          acc[i][j] = __builtin_amdgcn_mfma_f32_16x16x32_bf16(a[i], b[j], acc[i][j], 0, 0, 0);
    }
    __syncthreads();
  }
  #pragma unroll
  for (int i = 0; i < 4; ++i)
    #pragma unroll
    for (int j = 0; j < 4; ++j)
      #pragma unroll
      for (int rg = 0; rg < 4; ++rg) {
        int m = m0 + wm + i * 16 + kb * 4 + rg;
        int n = n0 + wn + j * 16 + fr;
        out[(size_t)m * NV + n] = acc[i][j][rg];
      }
}

extern "C" void kernel_launch(void* const* d_in, const int* in_sizes, int n_in,
                              void* d_out, int out_size, void* d_ws, size_t ws_size,
                              hipStream_t stream) {
  const int* tokens = (const int*)d_in[0];
  const float* embed = (const float*)d_in[1];
  const float* Wp = (const float*)d_in[2];
  const float* Wb = (const float*)d_in[3];
  const float* bang = (const float*)d_in[4];
  const float* agw = (const float*)d_in[5];
  const float* scales = (const float*)d_in[6];
  const float* shifts = (const float*)d_in[7];
  const float* normw = (const float*)d_in[8];
  const float* decay = (const float*)d_in[9];
  const float* gatew = (const float*)d_in[10];
  const float* onorm = (const float*)d_in[11];
  const float* lmw = (const float*)d_in[12];
  float* out = (float*)d_out;

  char* ws = (char*)d_ws;
  const size_t MB = 1u << 20;
  float* x = (float*)ws;                           // 4 MB
  u16* xh = (u16*)(ws + 4 * MB);                   // 2 MB
  u16* xl = (u16*)(ws + 6 * MB);                   // 2 MB
  float* Rf = (float*)(ws + 8 * MB);               // 4 MB
  u16* Rh = (u16*)(ws + 12 * MB);                  // 2 MB
  u16* Rl = (u16*)(ws + 14 * MB);                  // 2 MB
  float* trig = (float*)(ws + 16 * MB);            // 512 B
  float* cp = (float*)(ws + 17 * MB);              // 1 MB
  float* pacc = (float*)(ws + 18 * MB);            // 2 MB
  u16* xn = (u16*)(ws + 20 * MB);                  // 2 MB
  u16* gate_h = (u16*)(ws + 22 * MB);              // 2 MB
  u16* gate_l = (u16*)(ws + 24 * MB);              // 2 MB
  u16* Wp_h = (u16*)(ws + 26 * MB);                // 7 MB
  u16* Wp_l = (u16*)(ws + 33 * MB);                // 7 MB
  u16* Wb_h = (u16*)(ws + 40 * MB);                // 7 MB
  u16* Wb_l = (u16*)(ws + 47 * MB);                // 7 MB
  u16* lm_bf = (u16*)(ws + 54 * MB);               // 311 MB (optional)

  const size_t lm_elems = (size_t)NV * D;
  bool preconv = ws_size >= 54 * MB + lm_elems * 2;

  // weight preprocessing
  k_cvt2<<<512, 256, 0, stream>>>(gatew, gate_h, gate_l, (size_t)D * D / 4);
  k_cvt2<<<1024, 256, 0, stream>>>(Wp, Wp_h, Wp_l, (size_t)NCYC * 128 * D / 4);
  k_cvt2<<<1024, 256, 0, stream>>>(Wb, Wb_h, Wb_l, (size_t)NCYC * 128 * D / 4);
  if (preconv) k_cvt<<<2048, 256, 0, stream>>>(lmw, lm_bf, lm_elems / 4);

  fb_gather<<<256, 256, 0, stream>>>(tokens, embed, x, xh, xl, cp);
  for (int i = 0; i < NCYC; ++i) {
    const u16* Wph = Wp_h + (size_t)i * 128 * D;
    const u16* Wpl = Wp_l + (size_t)i * 128 * D;
    const u16* Wbh = Wb_h + (size_t)i * 128 * D;
    const u16* Wbl = Wb_l + (size_t)i * 128 * D;
    if ((i & 3) == 0) {
      fb_causal<<<256, 256, 0, stream>>>(x, Rh, Rl, decay);
      fb_gate<<<256, 256, 0, stream>>>(Rh, Rl, gate_h, gate_l, x, xh, xl);
    }
    fb_projang<<<128, 256, 0, stream>>>(xh, xl, Wph, Wpl, cp, agw, bang + i * 64,
                                        pacc, trig);
    fb_back<<<256, 256, 0, stream>>>(pacc, trig, Wbh, Wbl, Rf);
    fb_epi<<<256, 256, 0, stream>>>(x, xh, xl, Rf, scales + i * D, shifts + i * D,
                                    normw + i * D, cp);
  }
  fb_outnorm<<<256, 256, 0, stream>>>(x, onorm, xn);

  if (preconv)
    k_lm<true><<<9496, 256, 0, stream>>>(xn, lm_bf, out);
  else
    k_lm<false><<<9496, 256, 0, stream>>>(xn, lmw, out);
}

// Round 13
// 2821.962 us; speedup vs baseline: 2.5247x; 1.0579x over previous
//
#include <hip/hip_runtime.h>

typedef __attribute__((ext_vector_type(4))) float f32x4;
typedef __attribute__((ext_vector_type(8))) short bf16x8;
typedef unsigned short u16;
typedef unsigned int u32;
typedef __attribute__((ext_vector_type(4))) unsigned short u16x4;

#define EPS 1.1920929e-07f
#define S 1024
#define D 1024
#define NV 151936
#define NCYC 28
#define SMEM_BYTES 49152

__device__ __forceinline__ u16 f2bf(float f) {  // RNE
  u32 u = __float_as_uint(f);
  return (u16)((u + 0x7fffu + ((u >> 16) & 1u)) >> 16);
}
__device__ __forceinline__ float bf2f(u16 h) {
  return __uint_as_float((u32)h << 16);
}
struct bfpair { u16 h, l; };
__device__ __forceinline__ bfpair split_bf(float v) {
  bfpair r;
  r.h = f2bf(v);
  r.l = f2bf(v - bf2f(r.h));
  return r;
}

__device__ __forceinline__ void gl16(const void* g, void* s) {
  __builtin_amdgcn_global_load_lds((const __attribute__((address_space(1))) u32*)g,
                                   (__attribute__((address_space(3))) u32*)s, 16, 0, 0);
}

// safe for repeated calls (sync protects sbuf reuse)
__device__ __forceinline__ float block_sum256(float v, float* sbuf) {
  #pragma unroll
  for (int off = 32; off; off >>= 1) v += __shfl_down(v, off);
  int lane = threadIdx.x & 63, w = threadIdx.x >> 6;
  __syncthreads();
  if (lane == 0) sbuf[w] = v;
  __syncthreads();
  return sbuf[0] + sbuf[1] + sbuf[2] + sbuf[3];
}

// ---------------- f32 -> bf16 (RNE) ----------------
__global__ void k_cvt(const float* __restrict__ src, u16* __restrict__ dst, size_t n4) {
  size_t i = (size_t)blockIdx.x * 256 + threadIdx.x;
  size_t stride = (size_t)gridDim.x * 256;
  for (; i < n4; i += stride) {
    f32x4 v = ((const f32x4*)src)[i];
    u16x4 o;
    #pragma unroll
    for (int e = 0; e < 4; ++e) o[e] = f2bf(v[e]);
    ((u16x4*)dst)[i] = o;
  }
}

// ---------------- f32 -> (hi, lo) bf16 split ----------------
__global__ void k_cvt2(const float* __restrict__ src, u16* __restrict__ dh,
                       u16* __restrict__ dl, size_t n4) {
  size_t i = (size_t)blockIdx.x * 256 + threadIdx.x;
  size_t stride = (size_t)gridDim.x * 256;
  for (; i < n4; i += stride) {
    f32x4 v = ((const f32x4*)src)[i];
    u16x4 oh, ol;
    #pragma unroll
    for (int e = 0; e < 4; ++e) { bfpair p = split_bf(v[e]); oh[e] = p.h; ol[e] = p.l; }
    ((u16x4*)dh)[i] = oh;
    ((u16x4*)dl)[i] = ol;
  }
}

// ================= device phases =================

// gather + initial colpart; blocks 0..255
__device__ void gather_phase(const int* tokens, const float* embed,
                             float* x, u16* xh, u16* xl, float* cp) {
  const int t = threadIdx.x;
  if (blockIdx.x >= 256) return;
  f32x4 creg = 0.f;
  for (int rr = 0; rr < 4; ++rr) {
    int s = blockIdx.x * 4 + rr;
    int tok = tokens[s];
    f32x4 v = ((const f32x4*)(embed + (size_t)tok * D))[t];
    u16x4 oh, ol;
    #pragma unroll
    for (int e = 0; e < 4; ++e) { bfpair p = split_bf(v[e]); oh[e] = p.h; ol[e] = p.l; }
    ((f32x4*)(x + (size_t)s * D))[t] = v;
    ((u16x4*)(xh + (size_t)s * D))[t] = oh;
    ((u16x4*)(xl + (size_t)s * D))[t] = ol;
    creg += v;
  }
  *(f32x4*)(cp + (size_t)blockIdx.x * D + t * 4) = creg;
}

// 64x64-tile split-bf16 GEMM over 1024xD output, 256 tiles, single-buffered (32 KB)
template <bool CADD>
__device__ void gemm64_phase(char* smem, const u16* Ah_, const u16* Al_,
                             const u16* Bh_, const u16* Bl_, int K,
                             float* xout, u16* xho, u16* xlo, float* Cout, int G) {
  const int t = threadIdx.x;
  u16* Ash = (u16*)smem;          // 4096 u16 each
  u16* Asl = Ash + 4096;
  u16* Bsh = Asl + 4096;
  u16* Bsl = Bsh + 4096;
  const int wave = t >> 6, lane = t & 63;
  const int fr = lane & 15, kb = lane >> 4;
  const int sr = t >> 3, skc = (t & 7) << 3;
  const int sswz = skc ^ ((sr & 7) << 3);
  for (int tile = blockIdx.x; tile < 256; tile += G) {
    const int m0 = (tile >> 4) * 64, n0 = (tile & 15) * 64;
    f32x4 acc[4];
    #pragma unroll
    for (int j = 0; j < 4; ++j) acc[j] = 0.f;

    for (int k0 = 0; k0 < K; k0 += 64) {
      #pragma unroll
      for (int it = 0; it < 2; ++it) {
        int r = it * 32 + sr;
        size_t ga = (size_t)(m0 + r) * K + k0 + sswz;
        size_t gb = (size_t)(n0 + r) * K + k0 + sswz;
        int so = r * 64 + skc;
        gl16(Ah_ + ga, Ash + so);
        gl16(Al_ + ga, Asl + so);
        gl16(Bh_ + gb, Bsh + so);
        gl16(Bl_ + gb, Bsl + so);
      }
      __syncthreads();
      #pragma unroll
      for (int ks = 0; ks < 2; ++ks) {
        const int cphys = (ks * 32 + kb * 8) ^ ((fr & 7) << 3);
        int oa = (wave * 16 + fr) * 64 + cphys;
        bf16x8 ah = *(const bf16x8*)&Ash[oa];
        bf16x8 al = *(const bf16x8*)&Asl[oa];
        #pragma unroll
        for (int j = 0; j < 4; ++j) {
          int ob = (j * 16 + fr) * 64 + cphys;
          bf16x8 bh = *(const bf16x8*)&Bsh[ob];
          bf16x8 bl = *(const bf16x8*)&Bsl[ob];
          acc[j] = __builtin_amdgcn_mfma_f32_16x16x32_bf16(ah, bh, acc[j], 0, 0, 0);
          acc[j] = __builtin_amdgcn_mfma_f32_16x16x32_bf16(ah, bl, acc[j], 0, 0, 0);
          acc[j] = __builtin_amdgcn_mfma_f32_16x16x32_bf16(al, bh, acc[j], 0, 0, 0);
        }
      }
      __syncthreads();
    }
    #pragma unroll
    for (int j = 0; j < 4; ++j)
      #pragma unroll
      for (int rg = 0; rg < 4; ++rg) {
        int m = m0 + wave * 16 + kb * 4 + rg;
        int n = n0 + j * 16 + fr;
        if (CADD) {
          float v = xout[(size_t)m * D + n] + acc[j][rg];
          xout[(size_t)m * D + n] = v;
          bfpair p = split_bf(v);
          xho[(size_t)m * D + n] = p.h;
          xlo[(size_t)m * D + n] = p.l;
        } else {
          Cout[(size_t)m * D + n] = acc[j][rg];
        }
      }
  }
}

// causal EMA windowed conv -> split; 256 tiles of 64x64 (40.7 KB smem)
__device__ void causal_phase(char* smem, const float* x, u16* Rh, u16* Rl,
                             float dec, int G) {
  const int t = threadIdx.x;
  for (int tile = blockIdx.x; tile < 256; tile += G) {
    int s0 = (tile >> 4) * 64, d0 = (tile & 15) * 64;
    float (*tl)[64] = (float(*)[64])smem;  // [159][64]
    for (int idx = t; idx < 159 * 64; idx += 256) {
      int rr = idx >> 6, c = idx & 63;
      int gs = s0 - 95 + rr;
      tl[rr][c] = (gs >= 0) ? x[(size_t)gs * D + d0 + c] : 0.f;
    }
    __syncthreads();
    int c = t & 63, r0 = t >> 6;
    for (int rr = r0; rr < 64; rr += 4) {
      float acc = 0.f, w = 1.f - dec;
      int base = rr + 95;
      #pragma unroll 8
      for (int j = 0; j < 96; ++j) { acc += w * tl[base - j][c]; w *= dec; }
      bfpair p = split_bf(acc);
      Rh[(size_t)(s0 + rr) * D + d0 + c] = p.h;
      Rl[(size_t)(s0 + rr) * D + d0 + c] = p.l;
    }
    __syncthreads();
  }
}

// proj GEMM, k-split x16: blocks 0..255 = (mt = b&15, kq = b>>4), one K=64 step
__device__ void proj_phase(char* smem, const u16* xh, const u16* xl,
                           const u16* Bh_, const u16* Bl_, float* pacc) {
  const int t = threadIdx.x;
  const int mt = blockIdx.x & 15, kq = blockIdx.x >> 4;
  const int m0 = mt * 64;
  const int k0 = kq * 64;
  u16* Ash = (u16*)smem;       // 4096 u16
  u16* Asl = Ash + 4096;
  u16* Bsh = Asl + 4096;       // 8192 u16
  u16* Bsl = Bsh + 8192;
  const int wave = t >> 6, lane = t & 63;
  const int fr = lane & 15, kb = lane >> 4;
  const int sr = t >> 3, skc = (t & 7) << 3;
  const int sswz = skc ^ ((sr & 7) << 3);
  f32x4 acc[8];
  #pragma unroll
  for (int j = 0; j < 8; ++j) acc[j] = 0.f;

  #pragma unroll
  for (int it = 0; it < 2; ++it) {
    int r = it * 32 + sr;
    size_t ga = (size_t)(m0 + r) * D + k0 + sswz;
    gl16(xh + ga, Ash + r * 64 + skc);
    gl16(xl + ga, Asl + r * 64 + skc);
  }
  #pragma unroll
  for (int it = 0; it < 4; ++it) {
    int r = it * 32 + sr;
    size_t gb = (size_t)r * D + k0 + sswz;
    gl16(Bh_ + gb, Bsh + r * 64 + skc);
    gl16(Bl_ + gb, Bsl + r * 64 + skc);
  }
  __syncthreads();
  #pragma unroll
  for (int ks = 0; ks < 2; ++ks) {
    const int cphys = (ks * 32 + kb * 8) ^ ((fr & 7) << 3);
    int oa = (wave * 16 + fr) * 64 + cphys;
    bf16x8 ah = *(const bf16x8*)&Ash[oa];
    bf16x8 al = *(const bf16x8*)&Asl[oa];
    #pragma unroll
    for (int j = 0; j < 8; ++j) {
      int ob = (j * 16 + fr) * 64 + cphys;
      bf16x8 bh = *(const bf16x8*)&Bsh[ob];
      bf16x8 bl = *(const bf16x8*)&Bsl[ob];
      acc[j] = __builtin_amdgcn_mfma_f32_16x16x32_bf16(ah, bh, acc[j], 0, 0, 0);
      acc[j] = __builtin_amdgcn_mfma_f32_16x16x32_bf16(ah, bl, acc[j], 0, 0, 0);
      acc[j] = __builtin_amdgcn_mfma_f32_16x16x32_bf16(al, bh, acc[j], 0, 0, 0);
    }
  }
  float* pb = pacc + (size_t)blockIdx.x * 64 * 128;
  #pragma unroll
  for (int j = 0; j < 8; ++j)
    #pragma unroll
    for (int rg = 0; rg < 4; ++rg) {
      int ml = wave * 16 + kb * 4 + rg;
      pb[ml * 128 + j * 16 + fr] = acc[j][rg];
    }
}

// angles for ALL 64 planes in one block (reads cp from previous kernel)
__device__ void angles_all(float* colsum, const float* cp, const float* agw,
                           const float* bang_i, float* trig) {
  const int t = threadIdx.x;
  f32x4 acc = 0.f;
  for (int b = 0; b < 256; ++b)
    acc += *(const f32x4*)(cp + (size_t)b * D + t * 4);
  *(f32x4*)&colsum[t * 4] = acc;
  __syncthreads();
  const int wave = t >> 6, lane = t & 63;
  for (int pp = 0; pp < 16; ++pp) {
    int p = wave * 16 + pp;
    float sum = 0.f;
    #pragma unroll
    for (int q = 0; q < 16; ++q) {
      int d = lane + q * 64;
      sum += colsum[d] * agw[p * D + d];
    }
    #pragma unroll
    for (int off = 32; off; off >>= 1) sum += __shfl_down(sum, off);
    if (lane == 0) {
      float ang = bang_i[p] + 0.1f * (sum * (1.f / (float)S));
      trig[p] = cosf(ang);
      trig[64 + p] = sinf(ang);
    }
  }
}

// epilogue (+ fused colpart): blocks 0..255, 4 rows each
__device__ void epilogue_phase(float* sbuf, float* x, u16* xh, u16* xl,
                               const float* Rf, const float* scale,
                               const float* shift, const float* nw, float* cp) {
  const int t = threadIdx.x;
  if (blockIdx.x >= 256) return;
  f32x4 sc = *(const f32x4*)(scale + t * 4);
  f32x4 sh = *(const f32x4*)(shift + t * 4);
  f32x4 nwv = *(const f32x4*)(nw + t * 4);
  f32x4 creg = 0.f;
  for (int rr = 0; rr < 4; ++rr) {
    int s = blockIdx.x * 4 + rr;
    f32x4 xv = *(const f32x4*)(x + (size_t)s * D + t * 4);
    f32x4 rv = *(const f32x4*)(Rf + (size_t)s * D + t * 4);
    float y[4], ss = 0.f;
    #pragma unroll
    for (int c = 0; c < 4; ++c) {
      float xr = xv[c] + rv[c];
      float tt = xr * sc[c] + sh[c];
      float act = tt / (1.f + expf(-tt));
      y[c] = act - xv[c];
      ss += y[c] * y[c];
    }
    float total = block_sum256(ss, sbuf);
    float inv = rsqrtf(total * (1.f / (float)D) + EPS);
    f32x4 o;
    u16x4 oh, ol;
    #pragma unroll
    for (int c = 0; c < 4; ++c) {
      o[c] = xv[c] + y[c] * inv * nwv[c];
      bfpair p = split_bf(o[c]);
      oh[c] = p.h;
      ol[c] = p.l;
      creg[c] += o[c];
    }
    *(f32x4*)(x + (size_t)s * D + t * 4) = o;
    *(u16x4*)(xh + (size_t)s * D + t * 4) = oh;
    *(u16x4*)(xl + (size_t)s * D + t * 4) = ol;
  }
  *(f32x4*)(cp + (size_t)blockIdx.x * D + t * 4) = creg;
}

// final rmsnorm -> bf16: blocks 0..255, 4 rows each
__device__ void outnorm_phase(float* sbuf, const float* x, const float* w, u16* xn) {
  const int t = threadIdx.x;
  if (blockIdx.x >= 256) return;
  for (int rr = 0; rr < 4; ++rr) {
    int s = blockIdx.x * 4 + rr;
    f32x4 xv = *(const f32x4*)(x + (size_t)s * D + t * 4);
    float total = block_sum256(xv[0]*xv[0] + xv[1]*xv[1] + xv[2]*xv[2] + xv[3]*xv[3], sbuf);
    float inv = rsqrtf(total * (1.f / (float)D) + EPS);
    f32x4 wv = *(const f32x4*)(w + t * 4);
    u16x4 o;
    #pragma unroll
    for (int c = 0; c < 4; ++c) o[c] = f2bf(xv[c] * inv * wv[c]);
    *(u16x4*)(xn + (size_t)s * D + t * 4) = o;
  }
}

// ================= kernel wrappers =================
__global__ __launch_bounds__(256) void fb_gather(const int* tokens, const float* embed,
                                                 float* x, u16* xh, u16* xl, float* cp) {
  gather_phase(tokens, embed, x, xh, xl, cp);
}
__global__ __launch_bounds__(256) void fb_causal(const float* x, u16* Rh, u16* Rl,
                                                 const float* decay) {
  __shared__ __align__(16) char sm[40704];
  causal_phase(sm, x, Rh, Rl, 1.f / (1.f + expf(-decay[0])), gridDim.x);
}
__global__ __launch_bounds__(256) void fb_gate(const u16* Rh, const u16* Rl,
                                               const u16* gh, const u16* gl,
                                               float* x, u16* xh, u16* xl) {
  __shared__ __align__(16) char sm[32768];
  gemm64_phase<true>(sm, Rh, Rl, gh, gl, 1024, x, xh, xl, nullptr, gridDim.x);
}
// grid 257: blocks 0..255 proj (k-split x16), block 256 angles (all planes)
__global__ __launch_bounds__(256) void fb_proj(const u16* xh, const u16* xl,
                                               const u16* Wph, const u16* Wpl,
                                               const float* cp, const float* agw,
                                               const float* bang_i,
                                               float* pacc, float* trig) {
  __shared__ __align__(16) char sm[SMEM_BYTES];
  if (blockIdx.x < 256) proj_phase(sm, xh, xl, Wph, Wpl, pacc);
  else angles_all((float*)sm, cp, agw, bang_i, trig);
}

// back GEMM with FUSED rotation: A-tile (64x128 rot) computed from pacc+trig into LDS.
// LDS convention (matches gemm64): phys_slot = logical_col ^ ((row&7)<<3).
__global__ __launch_bounds__(256) void fb_back(const float* __restrict__ pacc,
                                               const float* __restrict__ trig,
                                               const u16* __restrict__ Bh_,
                                               const u16* __restrict__ Bl_,
                                               float* __restrict__ Rf) {
  __shared__ u16 Ash[64 * 128];   // 16 KB
  __shared__ u16 Asl[64 * 128];   // 16 KB
  __shared__ u16 Bsh[64 * 64];    // 8 KB
  __shared__ u16 Bsl[64 * 64];    // 8 KB
  const int t = threadIdx.x;
  const int tile = blockIdx.x;
  const int mt = tile >> 4;
  const int m0 = mt * 64, n0 = (tile & 15) * 64;
  const int wave = t >> 6, lane = t & 63;
  const int fr = lane & 15, kb = lane >> 4;
  const int sr = t >> 3, skc = (t & 7) << 3;
  const int sswz = skc ^ ((sr & 7) << 3);

  // ---- build rotated A tile: LOAD logical cols skc..skc+7, STORE at swizzled slot --
  #pragma unroll
  for (int ri = 0; ri < 2; ++ri) {
    int r = ri * 32 + sr;
    int pdst = skc ^ ((r & 7) << 3);  // physical slot for logical block skc
    f32x4 a0 = 0.f, a1 = 0.f, b0 = 0.f, b1 = 0.f;
    #pragma unroll
    for (int kq = 0; kq < 16; ++kq) {
      const float* pk = pacc + ((size_t)(kq * 16 + mt) * 64 + r) * 128;
      a0 += *(const f32x4*)(pk + skc);
      a1 += *(const f32x4*)(pk + skc + 4);
      b0 += *(const f32x4*)(pk + 64 + skc);
      b1 += *(const f32x4*)(pk + 64 + skc + 4);
    }
    #pragma unroll
    for (int kh = 0; kh < 2; ++kh) {
      u16 hbuf[8], lbuf[8];
      #pragma unroll
      for (int j = 0; j < 8; ++j) {
        float av = (j < 4) ? a0[j & 3] : a1[j & 3];
        float bv = (j < 4) ? b0[j & 3] : b1[j & 3];
        float ca = trig[skc + j], sa = trig[64 + skc + j];
        float v = (kh == 0) ? (av * ca - bv * sa) : (av * sa + bv * ca);
        bfpair p = split_bf(v);
        hbuf[j] = p.h;
        lbuf[j] = p.l;
      }
      int so = r * 128 + kh * 64 + pdst;
      *(bf16x8*)&Ash[so] = *(bf16x8*)hbuf;
      *(bf16x8*)&Asl[so] = *(bf16x8*)lbuf;
    }
  }
  __syncthreads();

  f32x4 acc[4];
  #pragma unroll
  for (int j = 0; j < 4; ++j) acc[j] = 0.f;

  for (int kt = 0; kt < 2; ++kt) {
    int k0 = kt * 64;
    #pragma unroll
    for (int it = 0; it < 2; ++it) {
      int r = it * 32 + sr;
      size_t gb = (size_t)(n0 + r) * 128 + k0 + sswz;
      gl16(Bh_ + gb, Bsh + r * 64 + skc);
      gl16(Bl_ + gb, Bsl + r * 64 + skc);
    }
    __syncthreads();
    #pragma unroll
    for (int ks = 0; ks < 2; ++ks) {
      const int w = (ks * 32 + kb * 8) ^ ((fr & 7) << 3);
      int oa = (wave * 16 + fr) * 128 + k0 + w;
      bf16x8 ah = *(const bf16x8*)&Ash[oa];
      bf16x8 al = *(const bf16x8*)&Asl[oa];
      #pragma unroll
      for (int j = 0; j < 4; ++j) {
        int ob = (j * 16 + fr) * 64 + w;
        bf16x8 bh = *(const bf16x8*)&Bsh[ob];
        bf16x8 bl = *(const bf16x8*)&Bsl[ob];
        acc[j] = __builtin_amdgcn_mfma_f32_16x16x32_bf16(ah, bh, acc[j], 0, 0, 0);
        acc[j] = __builtin_amdgcn_mfma_f32_16x16x32_bf16(ah, bl, acc[j], 0, 0, 0);
        acc[j] = __builtin_amdgcn_mfma_f32_16x16x32_bf16(al, bh, acc[j], 0, 0, 0);
      }
    }
    __syncthreads();
  }
  #pragma unroll
  for (int j = 0; j < 4; ++j)
    #pragma unroll
    for (int rg = 0; rg < 4; ++rg) {
      int m = m0 + wave * 16 + kb * 4 + rg;
      int n = n0 + j * 16 + fr;
      Rf[(size_t)m * D + n] = acc[j][rg];
    }
}

__global__ __launch_bounds__(256) void fb_epi(float* x, u16* xh, u16* xl, const float* Rf,
                                              const float* scale, const float* shift,
                                              const float* nw, float* cp) {
  __shared__ float sbuf[4];
  epilogue_phase(sbuf, x, xh, xl, Rf, scale, shift, nw, cp);
}
__global__ __launch_bounds__(256) void fb_outnorm(const float* x, const float* w, u16* xn) {
  __shared__ float sbuf[4];
  outnorm_phase(sbuf, x, w, xn);
}

// ---------------- lm_head GEMM, m97-style LDS + T2 swizzle, XCD-chunk swizzle ------
// grid: 9496 = 8 m-tiles x 1187 n-tiles (1-D).
template <bool PRECONV>
__global__ __launch_bounds__(256) void k_lm(const u16* __restrict__ A,
                                            const void* __restrict__ Wsrc,
                                            float* __restrict__ out) {
  __shared__ u16 As[128 * 64];
  __shared__ u16 Bs[128 * 64];
  const int bid = blockIdx.x;
  const int lid = (bid & 7) * 1187 + (bid >> 3);  // bijective: 9496 = 8*1187
  const int m0 = (lid & 7) * 128;
  const int n0 = (lid >> 3) * 128;
  const int t = threadIdx.x;
  const int wave = t >> 6, lane = t & 63;
  const int wm = (wave >> 1) * 64, wn = (wave & 1) * 64;
  const int fr = lane & 15, kb = lane >> 4;
  const int sr = t >> 3, skc = (t & 7) << 3;
  const int sswz = skc ^ ((sr & 7) << 3);
  const u16* Wb16 = (const u16*)Wsrc;
  const float* Wf = (const float*)Wsrc;
  f32x4 acc[4][4];
  #pragma unroll
  for (int i = 0; i < 4; ++i)
    #pragma unroll
    for (int j = 0; j < 4; ++j) acc[i][j] = 0.f;

  for (int k0 = 0; k0 < D; k0 += 64) {
    #pragma unroll
    for (int it = 0; it < 4; ++it) {
      int r = it * 32 + sr;
      gl16(A + (size_t)(m0 + r) * D + k0 + sswz, As + r * 64 + skc);
    }
    if (PRECONV) {
      #pragma unroll
      for (int it = 0; it < 4; ++it) {
        int r = it * 32 + sr;
        gl16(Wb16 + (size_t)(n0 + r) * D + k0 + sswz, Bs + r * 64 + skc);
      }
    } else {
      #pragma unroll
      for (int it = 0; it < 4; ++it) {
        int r = it * 32 + sr;
        const float* src = Wf + (size_t)(n0 + r) * D + k0 + sswz;
        f32x4 v0 = *(const f32x4*)src;
        f32x4 v1 = *(const f32x4*)(src + 4);
        u16 h[8];
        #pragma unroll
        for (int e = 0; e < 4; ++e) { h[e] = f2bf(v0[e]); h[e + 4] = f2bf(v1[e]); }
        *(bf16x8*)&Bs[r * 64 + skc] = *(bf16x8*)h;
      }
    }
    __syncthreads();
    #pragma unroll
    for (int ks = 0; ks < 2; ++ks) {
      const int cphys = (ks * 32 + kb * 8) ^ ((fr & 7) << 3);
      bf16x8 a[4], b[4];
      #pragma unroll
      for (int i = 0; i < 4; ++i) a[i] = *(const bf16x8*)&As[(wm + i * 16 + fr) * 64 + cphys];
      #pragma unroll
      for (int j = 0; j < 4; ++j) b[j] = *(const bf16x8*)&Bs[(wn + j * 16 + fr) * 64 + cphys];
      #pragma unroll
      for (int i = 0; i < 4; ++i)
        #pragma unroll
        for (int j = 0; j < 4; ++j)
          acc[i][j] = __builtin_amdgcn_mfma_f32_16x16x32_bf16(a[i], b[j], acc[i][j], 0, 0, 0);
    }
    __syncthreads();
  }
  #pragma unroll
  for (int i = 0; i < 4; ++i)
    #pragma unroll
    for (int j = 0; j < 4; ++j)
      #pragma unroll
      for (int rg = 0; rg < 4; ++rg) {
        int m = m0 + wm + i * 16 + kb * 4 + rg;
        int n = n0 + wn + j * 16 + fr;
        out[(size_t)m * NV + n] = acc[i][j][rg];
      }
}

extern "C" void kernel_launch(void* const* d_in, const int* in_sizes, int n_in,
                              void* d_out, int out_size, void* d_ws, size_t ws_size,
                              hipStream_t stream) {
  const int* tokens = (const int*)d_in[0];
  const float* embed = (const float*)d_in[1];
  const float* Wp = (const float*)d_in[2];
  const float* Wb = (const float*)d_in[3];
  const float* bang = (const float*)d_in[4];
  const float* agw = (const float*)d_in[5];
  const float* scales = (const float*)d_in[6];
  const float* shifts = (const float*)d_in[7];
  const float* normw = (const float*)d_in[8];
  const float* decay = (const float*)d_in[9];
  const float* gatew = (const float*)d_in[10];
  const float* onorm = (const float*)d_in[11];
  const float* lmw = (const float*)d_in[12];
  float* out = (float*)d_out;

  char* ws = (char*)d_ws;
  const size_t MB = 1u << 20;
  float* x = (float*)ws;                           // 4 MB
  u16* xh = (u16*)(ws + 4 * MB);                   // 2 MB
  u16* xl = (u16*)(ws + 6 * MB);                   // 2 MB
  float* Rf = (float*)(ws + 8 * MB);               // 4 MB
  u16* Rh = (u16*)(ws + 12 * MB);                  // 2 MB
  u16* Rl = (u16*)(ws + 14 * MB);                  // 2 MB
  float* trig = (float*)(ws + 16 * MB);            // 512 B
  float* cp = (float*)(ws + 17 * MB);              // 1 MB
  u16* xn = (u16*)(ws + 20 * MB);                  // 2 MB
  u16* gate_h = (u16*)(ws + 22 * MB);              // 2 MB
  u16* gate_l = (u16*)(ws + 24 * MB);              // 2 MB
  u16* Wp_h = (u16*)(ws + 26 * MB);                // 7 MB
  u16* Wp_l = (u16*)(ws + 33 * MB);                // 7 MB
  u16* Wb_h = (u16*)(ws + 40 * MB);                // 7 MB
  u16* Wb_l = (u16*)(ws + 47 * MB);                // 7 MB
  float* pacc = (float*)(ws + 54 * MB);            // 8 MB (256 x 64x128 f32)
  u16* lm_bf = (u16*)(ws + 62 * MB);               // 311 MB (optional)

  const size_t lm_elems = (size_t)NV * D;
  bool preconv = ws_size >= 62 * MB + lm_elems * 2;

  // weight preprocessing
  k_cvt2<<<512, 256, 0, stream>>>(gatew, gate_h, gate_l, (size_t)D * D / 4);
  k_cvt2<<<1024, 256, 0, stream>>>(Wp, Wp_h, Wp_l, (size_t)NCYC * 128 * D / 4);
  k_cvt2<<<1024, 256, 0, stream>>>(Wb, Wb_h, Wb_l, (size_t)NCYC * 128 * D / 4);
  if (preconv) k_cvt<<<2048, 256, 0, stream>>>(lmw, lm_bf, lm_elems / 4);

  fb_gather<<<256, 256, 0, stream>>>(tokens, embed, x, xh, xl, cp);
  for (int i = 0; i < NCYC; ++i) {
    const u16* Wph = Wp_h + (size_t)i * 128 * D;
    const u16* Wpl = Wp_l + (size_t)i * 128 * D;
    const u16* Wbh = Wb_h + (size_t)i * 128 * D;
    const u16* Wbl = Wb_l + (size_t)i * 128 * D;
    if ((i & 3) == 0) {
      fb_causal<<<256, 256, 0, stream>>>(x, Rh, Rl, decay);
      fb_gate<<<256, 256, 0, stream>>>(Rh, Rl, gate_h, gate_l, x, xh, xl);
    }
    fb_proj<<<257, 256, 0, stream>>>(xh, xl, Wph, Wpl, cp, agw, bang + i * 64,
                                     pacc, trig);
    fb_back<<<256, 256, 0, stream>>>(pacc, trig, Wbh, Wbl, Rf);
    fb_epi<<<256, 256, 0, stream>>>(x, xh, xl, Rf, scales + i * D, shifts + i * D,
                                    normw + i * D, cp);
  }
  fb_outnorm<<<256, 256, 0, stream>>>(x, onorm, xn);

  if (preconv)
    k_lm<true><<<9496, 256, 0, stream>>>(xn, lm_bf, out);
  else
    k_lm<false><<<9496, 256, 0, stream>>>(xn, lmw, out);
}